// Round 1
// baseline (3691.065 us; speedup 1.0000x reference)
//
#include <hip/hip_runtime.h>
#include <hip/hip_bf16.h>

// Problem: B=8, S=2048, D=1024, O=1024
//   qp = q@Wq, kp = k@Wk, vp = k@Wv          [S,O] per batch
//   attn = qp @ kp^T                          [S,S] per batch (NO 1/sqrt(d))
//   w = softmax(attn, axis=-1)
//   context[kk,o] = sum_q w[q,kk]*vp[q,o]     (attn^T @ v)
//   out = concat([q, context], -1)            [B,S,2048] fp32

#define BM 64
#define BN 64
#define BK 16

// opA: 0 = A is [M,K] row-major (k contig);  1 = A is [K,M] row-major (m contig)
// opB: 0 = B is [K,N] row-major (n contig);  1 = B is [N,K] row-major (k contig)
template<int opA, int opB>
__global__ __launch_bounds__(256)
void sgemm(const float* __restrict__ A, const float* __restrict__ B,
           float* __restrict__ C,
           int M, int N, int K, int lda, int ldb, int ldc)
{
    __shared__ float As[BK][BM];
    __shared__ float Bs[BK][BN];

    const int tid = threadIdx.x;       // 0..255
    const int tx = tid & 15;           // 16x16 thread grid
    const int ty = tid >> 4;
    const int bm = blockIdx.y * BM;
    const int bn = blockIdx.x * BN;

    float acc[4][4] = {};

    for (int k0 = 0; k0 < K; k0 += BK) {
        // ---- stage A tile ----
        if (opA == 0) {
            // rows of A are k-contiguous: float4 along k, transpose into LDS
            const int row = tid >> 2;              // 0..63
            const int kq  = (tid & 3) * 4;         // 0,4,8,12
            const float4 v = *reinterpret_cast<const float4*>(
                A + (long)(bm + row) * lda + (k0 + kq));
            As[kq + 0][row] = v.x;
            As[kq + 1][row] = v.y;
            As[kq + 2][row] = v.z;
            As[kq + 3][row] = v.w;
        } else {
            // A is [K,M], m-contiguous: float4 along m, direct store
            const int kk = tid >> 4;               // 0..15
            const int mq = (tid & 15) * 4;         // 0..60
            *reinterpret_cast<float4*>(&As[kk][mq]) =
                *reinterpret_cast<const float4*>(
                    A + (long)(k0 + kk) * lda + (bm + mq));
        }
        // ---- stage B tile ----
        if (opB == 0) {
            const int kk = tid >> 4;
            const int nq = (tid & 15) * 4;
            *reinterpret_cast<float4*>(&Bs[kk][nq]) =
                *reinterpret_cast<const float4*>(
                    B + (long)(k0 + kk) * ldb + (bn + nq));
        } else {
            // B is [N,K], k-contiguous: float4 along k, transpose into LDS
            const int row = tid >> 2;              // n index 0..63
            const int kq  = (tid & 3) * 4;
            const float4 v = *reinterpret_cast<const float4*>(
                B + (long)(bn + row) * ldb + (k0 + kq));
            Bs[kq + 0][row] = v.x;
            Bs[kq + 1][row] = v.y;
            Bs[kq + 2][row] = v.z;
            Bs[kq + 3][row] = v.w;
        }
        __syncthreads();

        #pragma unroll
        for (int kk = 0; kk < BK; ++kk) {
            const float4 a = *reinterpret_cast<const float4*>(&As[kk][ty * 4]);
            const float4 b = *reinterpret_cast<const float4*>(&Bs[kk][tx * 4]);
            const float av[4] = {a.x, a.y, a.z, a.w};
            const float bv[4] = {b.x, b.y, b.z, b.w};
            #pragma unroll
            for (int i = 0; i < 4; ++i)
                #pragma unroll
                for (int j = 0; j < 4; ++j)
                    acc[i][j] += av[i] * bv[j];
        }
        __syncthreads();
    }

    #pragma unroll
    for (int i = 0; i < 4; ++i) {
        const float4 v = make_float4(acc[i][0], acc[i][1], acc[i][2], acc[i][3]);
        *reinterpret_cast<float4*>(
            &C[(long)(bm + ty * 4 + i) * ldc + (bn + tx * 4)]) = v;
    }
}

__device__ __forceinline__ float wave_reduce_max(float v) {
    #pragma unroll
    for (int off = 1; off < 64; off <<= 1)
        v = fmaxf(v, __shfl_xor(v, off, 64));
    return v;
}
__device__ __forceinline__ float wave_reduce_sum(float v) {
    #pragma unroll
    for (int off = 1; off < 64; off <<= 1)
        v += __shfl_xor(v, off, 64);
    return v;
}

// One block per row; ncols fixed at 2048 (256 threads x 2 float4).
__global__ __launch_bounds__(256)
void softmax_rows2048(float* __restrict__ X)
{
    float* x = X + (long)blockIdx.x * 2048;
    const int tid = threadIdx.x;

    float4 v0 = *reinterpret_cast<const float4*>(&x[tid * 4]);
    float4 v1 = *reinterpret_cast<const float4*>(&x[1024 + tid * 4]);

    float m = fmaxf(fmaxf(fmaxf(v0.x, v0.y), fmaxf(v0.z, v0.w)),
                    fmaxf(fmaxf(v1.x, v1.y), fmaxf(v1.z, v1.w)));
    m = wave_reduce_max(m);

    __shared__ float sm[4];
    __shared__ float ss[4];
    const int wid = tid >> 6;
    if ((tid & 63) == 0) sm[wid] = m;
    __syncthreads();
    m = fmaxf(fmaxf(sm[0], sm[1]), fmaxf(sm[2], sm[3]));

    v0.x = expf(v0.x - m); v0.y = expf(v0.y - m);
    v0.z = expf(v0.z - m); v0.w = expf(v0.w - m);
    v1.x = expf(v1.x - m); v1.y = expf(v1.y - m);
    v1.z = expf(v1.z - m); v1.w = expf(v1.w - m);

    float s = (v0.x + v0.y + v0.z + v0.w) + (v1.x + v1.y + v1.z + v1.w);
    s = wave_reduce_sum(s);
    if ((tid & 63) == 0) ss[wid] = s;
    __syncthreads();
    s = ss[0] + ss[1] + ss[2] + ss[3];

    const float inv = 1.0f / s;
    v0.x *= inv; v0.y *= inv; v0.z *= inv; v0.w *= inv;
    v1.x *= inv; v1.y *= inv; v1.z *= inv; v1.w *= inv;

    *reinterpret_cast<float4*>(&x[tid * 4]) = v0;
    *reinterpret_cast<float4*>(&x[1024 + tid * 4]) = v1;
}

// Copy q [B*S,1024] into out[:, 0:1024] where out rows have stride 2048.
__global__ __launch_bounds__(256)
void copy_q_kernel(const float* __restrict__ q, float* __restrict__ out, long n4)
{
    const long idx = (long)blockIdx.x * 256 + threadIdx.x; // one float4 each
    if (idx >= n4) return;
    const long row = idx >> 8;          // 256 float4 per 1024-col row
    const long c4  = idx & 255;
    *reinterpret_cast<float4*>(&out[row * 2048 + c4 * 4]) =
        *reinterpret_cast<const float4*>(&q[row * 1024 + c4 * 4]);
}

extern "C" void kernel_launch(void* const* d_in, const int* in_sizes, int n_in,
                              void* d_out, int out_size, void* d_ws, size_t ws_size,
                              hipStream_t stream)
{
    const float* q  = (const float*)d_in[0];
    const float* k  = (const float*)d_in[1];
    const float* Wq = (const float*)d_in[2];
    const float* Wk = (const float*)d_in[3];
    const float* Wv = (const float*)d_in[4];
    float* out = (float*)d_out;

    const int B = 8, S = 2048, D = 1024, O = 1024;

    // workspace layout (floats): qp[S*O] kp[S*O] vp[S*O] attn[S*S]  = 40 MiB
    float* qp   = (float*)d_ws;
    float* kp   = qp + (size_t)S * O;
    float* vp   = kp + (size_t)S * O;
    float* attn = vp + (size_t)S * O;

    // out[:, :, 0:1024] = q
    {
        const long n4 = (long)B * S * D / 4;
        copy_q_kernel<<<dim3((n4 + 255) / 256), dim3(256), 0, stream>>>(q, out, n4);
    }

    const dim3 blk(256);
    const dim3 gproj(O / BN, S / BM);   // 16 x 32
    const dim3 gattn(S / BN, S / BM);   // 32 x 32
    const dim3 gctx (O / BN, S / BM);   // 16 x 32

    for (int b = 0; b < B; ++b) {
        const float* qb = q + (size_t)b * S * D;
        const float* kb = k + (size_t)b * S * D;
        float* outc = out + (size_t)b * S * 2048 + D;  // context goes to cols 1024..2047

        // projections: [S,D] @ [D,O]
        sgemm<0, 0><<<gproj, blk, 0, stream>>>(qb, Wq, qp, S, O, D, D, O, O);
        sgemm<0, 0><<<gproj, blk, 0, stream>>>(kb, Wk, kp, S, O, D, D, O, O);
        sgemm<0, 0><<<gproj, blk, 0, stream>>>(kb, Wv, vp, S, O, D, D, O, O);

        // attn = qp @ kp^T : [S,O] x [S,O]^T -> [S,S]
        sgemm<0, 1><<<gattn, blk, 0, stream>>>(qp, kp, attn, S, S, O, O, O, S);

        // softmax over last axis
        softmax_rows2048<<<dim3(S), blk, 0, stream>>>(attn);

        // context = attn_w^T @ vp : A is [K=S(q), M=S(kk)] m-contig, B=[S,O]
        sgemm<1, 0><<<gctx, blk, 0, stream>>>(attn, vp, outc, S, O, S, S, O, 2048);
    }
}

// Round 2
// 1241.098 us; speedup vs baseline: 2.9740x; 2.9740x over previous
//
#include <hip/hip_runtime.h>
#include <hip/hip_bf16.h>

// B=8, S=2048, D=1024, O=1024
// qp=q@Wq, kp=k@Wk, vp=k@Wv ; attn=qp@kp^T (no scale); w=softmax(attn,-1)
// context = attn_w^T @ vp ; out = concat([q, context], -1)  fp32 [B,S,2048]
//
// Split-bf16 strategy: x = hi + lo (both bf16). 3-term product
// hi*hi + hi*lo + lo*hi computed by ONE bf16 GEMM over K'=3K with
// A' = [hiA, hiA, loA], B' = [hiB, loB, hiB] packed along K.

typedef __attribute__((ext_vector_type(4))) float f32x4;
typedef __attribute__((ext_vector_type(8))) short bf16x8;
typedef __attribute__((ext_vector_type(8))) unsigned short u16x8;
typedef __attribute__((ext_vector_type(4))) unsigned short u16x4;

__device__ __forceinline__ unsigned short f2bf(float x) {
    union { float f; unsigned u; } u; u.f = x;
    unsigned r = u.u + 0x7fffu + ((u.u >> 16) & 1u);
    return (unsigned short)(r >> 16);
}
__device__ __forceinline__ float bf2f(unsigned short b) {
    union { unsigned u; float f; } u; u.u = ((unsigned)b) << 16;
    return u.f;
}

// ---------------------------------------------------------------------------
// Generic bf16 MFMA GEMM:  C = A @ B^T
//   A [M,K] row-major (k contig), B [N,K] row-major (k contig), bf16 (ushort)
//   128x128 tile, BK=32, 4 waves (2x2), 16x16x32 MFMA, global_load_lds x16.
// CMODE: 0 = fp32 C (ldc) | 1 = bf16 pack [hi,hi,lo] into [M,3N]
//        2 = bf16 pack [hi,lo,hi] into [M,3N] | 3 = bf16 C^T [N, ldc]
// z-batching: per-z element offsets az,bz,cz.
// ---------------------------------------------------------------------------
#define CM_F32    0
#define CM_PACK_A 1
#define CM_PACK_B 2
#define CM_BF16T  3

template<int CMODE>
__global__ __launch_bounds__(256)
void gemm_bf16(const unsigned short* __restrict__ A,
               const unsigned short* __restrict__ B,
               void* __restrict__ Cv,
               int M, int N, int K, int lda, int ldb, int ldc,
               long az, long bz, long cz)
{
    __shared__ unsigned short As[128 * 32];
    __shared__ unsigned short Bs[128 * 32];

    const int z = blockIdx.z;
    const char* Ab = (const char*)(A + z * az);
    const char* Bb = (const char*)(B + z * bz);

    const int tid = threadIdx.x;
    const int bm = blockIdx.y * 128;
    const int bn = blockIdx.x * 128;

    const int srow = (tid * 16) >> 6;   // 0..63 (row within half-tile)
    const int skb  = (tid * 16) & 63;   // byte offset within 64B row
    const int wave = tid >> 6;

    const int lane = tid & 63;
    const int r16 = lane & 15, half = lane >> 4;
    const int wr = wave >> 1, wc = wave & 1;

    f32x4 acc[4][4];
    #pragma unroll
    for (int i = 0; i < 4; ++i)
        #pragma unroll
        for (int j = 0; j < 4; ++j)
            acc[i][j] = f32x4{0.f, 0.f, 0.f, 0.f};

    for (int k0 = 0; k0 < K; k0 += 32) {
        // ---- stage A/B tiles: 8KB each via global_load_lds x16 ----
        {
            const char* ga0 = Ab + ((long)(bm + srow) * lda + k0) * 2 + skb;
            const char* ga1 = Ab + ((long)(bm + 64 + srow) * lda + k0) * 2 + skb;
            const char* gb0 = Bb + ((long)(bn + srow) * ldb + k0) * 2 + skb;
            const char* gb1 = Bb + ((long)(bn + 64 + srow) * ldb + k0) * 2 + skb;
            __builtin_amdgcn_global_load_lds(
                (const __attribute__((address_space(1))) void*)ga0,
                (__attribute__((address_space(3))) void*)((char*)As + wave * 1024),
                16, 0, 0);
            __builtin_amdgcn_global_load_lds(
                (const __attribute__((address_space(1))) void*)ga1,
                (__attribute__((address_space(3))) void*)((char*)As + 4096 + wave * 1024),
                16, 0, 0);
            __builtin_amdgcn_global_load_lds(
                (const __attribute__((address_space(1))) void*)gb0,
                (__attribute__((address_space(3))) void*)((char*)Bs + wave * 1024),
                16, 0, 0);
            __builtin_amdgcn_global_load_lds(
                (const __attribute__((address_space(1))) void*)gb1,
                (__attribute__((address_space(3))) void*)((char*)Bs + 4096 + wave * 1024),
                16, 0, 0);
        }
        __syncthreads();

        bf16x8 af[4], bfr[4];
        #pragma unroll
        for (int i = 0; i < 4; ++i)
            af[i] = *(const bf16x8*)(As + (wr * 64 + i * 16 + r16) * 32 + half * 8);
        #pragma unroll
        for (int j = 0; j < 4; ++j)
            bfr[j] = *(const bf16x8*)(Bs + (wc * 64 + j * 16 + r16) * 32 + half * 8);

        #pragma unroll
        for (int i = 0; i < 4; ++i)
            #pragma unroll
            for (int j = 0; j < 4; ++j)
                acc[i][j] = __builtin_amdgcn_mfma_f32_16x16x32_bf16(
                    af[i], bfr[j], acc[i][j], 0, 0, 0);
        __syncthreads();
    }

    // ---- epilogue: D mapping col=lane&15, row=(lane>>4)*4+r  [m89/m91] ----
    #pragma unroll
    for (int i = 0; i < 4; ++i) {
        #pragma unroll
        for (int j = 0; j < 4; ++j) {
            const int row0 = bm + wr * 64 + i * 16 + half * 4;
            const int col  = bn + wc * 64 + j * 16 + r16;
            if (CMODE == CM_F32) {
                float* C = (float*)Cv + z * cz;
                #pragma unroll
                for (int r = 0; r < 4; ++r)
                    C[(long)(row0 + r) * ldc + col] = acc[i][j][r];
            } else if (CMODE == CM_PACK_A || CMODE == CM_PACK_B) {
                unsigned short* C = (unsigned short*)Cv + z * cz;
                #pragma unroll
                for (int r = 0; r < 4; ++r) {
                    const float v = acc[i][j][r];
                    const unsigned short h = f2bf(v);
                    const unsigned short l = f2bf(v - bf2f(h));
                    const long base = (long)(row0 + r) * (3LL * N) + col;
                    if (CMODE == CM_PACK_A) {
                        C[base] = h; C[base + N] = h; C[base + 2 * N] = l;
                    } else {
                        C[base] = h; C[base + N] = l; C[base + 2 * N] = h;
                    }
                }
            } else { // CM_BF16T: C^T[col][row0..row0+3]
                unsigned short* C = (unsigned short*)Cv + z * cz;
                u16x4 v;
                #pragma unroll
                for (int r = 0; r < 4; ++r) v[r] = f2bf(acc[i][j][r]);
                *(u16x4*)(C + (long)col * ldc + row0) = v;
            }
        }
    }
}

// ---------------------------------------------------------------------------
// Pack fp32 rows [R,1024] -> bf16 [R,3072] in A-order [hi,hi,lo]
// ---------------------------------------------------------------------------
__global__ __launch_bounds__(256)
void pack_rows_A(const float* __restrict__ in, unsigned short* __restrict__ out,
                 long nquads)
{
    const long i = (long)blockIdx.x * 256 + threadIdx.x;
    if (i >= nquads) return;
    const long row = i >> 8;
    const int  c = (int)(i & 255) * 4;
    const float4 v = *(const float4*)(in + row * 1024 + c);
    const float vv[4] = {v.x, v.y, v.z, v.w};
    u16x4 h, l;
    #pragma unroll
    for (int j = 0; j < 4; ++j) {
        h[j] = f2bf(vv[j]);
        l[j] = f2bf(vv[j] - bf2f(h[j]));
    }
    unsigned short* o = out + row * 3072 + c;
    *(u16x4*)(o)        = h;
    *(u16x4*)(o + 1024) = h;
    *(u16x4*)(o + 2048) = l;
}

// ---------------------------------------------------------------------------
// W [1024(d),1024(o)] fp32 -> Wt [1024(o), 3072] bf16 in B-order [hi,lo,hi]
// (transpose via LDS tile)
// ---------------------------------------------------------------------------
__global__ __launch_bounds__(256)
void pack_W_T(const float* __restrict__ W, unsigned short* __restrict__ Wt)
{
    __shared__ float tile[64][65];
    const int d0 = blockIdx.y * 64, o0 = blockIdx.x * 64;
    const int t = threadIdx.x;
    const int rr = t >> 4, c4 = (t & 15) * 4;
    #pragma unroll
    for (int it = 0; it < 4; ++it) {
        const int r = rr + it * 16;
        const float4 v = *(const float4*)(W + (long)(d0 + r) * 1024 + o0 + c4);
        tile[r][c4] = v.x; tile[r][c4 + 1] = v.y;
        tile[r][c4 + 2] = v.z; tile[r][c4 + 3] = v.w;
    }
    __syncthreads();
    #pragma unroll
    for (int it = 0; it < 4; ++it) {
        const int orow = rr + it * 16;
        u16x4 h, l;
        #pragma unroll
        for (int j = 0; j < 4; ++j) {
            const float x = tile[c4 + j][orow];
            h[j] = f2bf(x);
            l[j] = f2bf(x - bf2f(h[j]));
        }
        unsigned short* o = Wt + (long)(o0 + orow) * 3072 + d0 + c4;
        *(u16x4*)(o)        = h;
        *(u16x4*)(o + 1024) = l;
        *(u16x4*)(o + 2048) = h;
    }
}

// ---------------------------------------------------------------------------
// Softmax over rows of 2048 (fp32 in) -> bf16 out
// ---------------------------------------------------------------------------
__device__ __forceinline__ float wave_reduce_max(float v) {
    #pragma unroll
    for (int off = 1; off < 64; off <<= 1)
        v = fmaxf(v, __shfl_xor(v, off, 64));
    return v;
}
__device__ __forceinline__ float wave_reduce_sum(float v) {
    #pragma unroll
    for (int off = 1; off < 64; off <<= 1)
        v += __shfl_xor(v, off, 64);
    return v;
}

__global__ __launch_bounds__(256)
void softmax_rows_bf16(const float* __restrict__ X, unsigned short* __restrict__ Y)
{
    const float* x = X + (long)blockIdx.x * 2048;
    unsigned short* y = Y + (long)blockIdx.x * 2048;
    const int tid = threadIdx.x;

    float4 v0 = *(const float4*)(x + tid * 4);
    float4 v1 = *(const float4*)(x + 1024 + tid * 4);

    float m = fmaxf(fmaxf(fmaxf(v0.x, v0.y), fmaxf(v0.z, v0.w)),
                    fmaxf(fmaxf(v1.x, v1.y), fmaxf(v1.z, v1.w)));
    m = wave_reduce_max(m);

    __shared__ float sm[4];
    __shared__ float ss[4];
    const int wid = tid >> 6;
    if ((tid & 63) == 0) sm[wid] = m;
    __syncthreads();
    m = fmaxf(fmaxf(sm[0], sm[1]), fmaxf(sm[2], sm[3]));

    v0.x = expf(v0.x - m); v0.y = expf(v0.y - m);
    v0.z = expf(v0.z - m); v0.w = expf(v0.w - m);
    v1.x = expf(v1.x - m); v1.y = expf(v1.y - m);
    v1.z = expf(v1.z - m); v1.w = expf(v1.w - m);

    float s = (v0.x + v0.y + v0.z + v0.w) + (v1.x + v1.y + v1.z + v1.w);
    s = wave_reduce_sum(s);
    if ((tid & 63) == 0) ss[wid] = s;
    __syncthreads();
    s = ss[0] + ss[1] + ss[2] + ss[3];

    const float inv = 1.0f / s;
    u16x4 o0, o1;
    o0[0] = f2bf(v0.x * inv); o0[1] = f2bf(v0.y * inv);
    o0[2] = f2bf(v0.z * inv); o0[3] = f2bf(v0.w * inv);
    o1[0] = f2bf(v1.x * inv); o1[1] = f2bf(v1.y * inv);
    o1[2] = f2bf(v1.z * inv); o1[3] = f2bf(v1.w * inv);
    *(u16x4*)(y + tid * 4) = o0;
    *(u16x4*)(y + 1024 + tid * 4) = o1;
}

// ---------------------------------------------------------------------------
// bf16 [2048,2048] transpose (per z), tiled 64x64 via LDS
// ---------------------------------------------------------------------------
__global__ __launch_bounds__(256)
void transpose_bf16_2048(const unsigned short* __restrict__ in,
                         unsigned short* __restrict__ out)
{
    __shared__ unsigned short tile[64][66];
    const long zoff = (long)blockIdx.z * 2048 * 2048;
    const int r0 = blockIdx.y * 64, c0 = blockIdx.x * 64;
    const int t = threadIdx.x;
    const int rr = t >> 3, seg = (t & 7) * 8;
    #pragma unroll
    for (int it = 0; it < 2; ++it) {
        const int r = rr + it * 32;
        u16x8 v = *(const u16x8*)(in + zoff + (long)(r0 + r) * 2048 + c0 + seg);
        #pragma unroll
        for (int j = 0; j < 8; ++j) tile[r][seg + j] = v[j];
    }
    __syncthreads();
    #pragma unroll
    for (int it = 0; it < 2; ++it) {
        const int r = rr + it * 32;
        u16x8 v;
        #pragma unroll
        for (int j = 0; j < 8; ++j) v[j] = tile[seg + j][r];
        *(u16x8*)(out + zoff + (long)(c0 + r) * 2048 + r0 + seg) = v;
    }
}

// ---------------------------------------------------------------------------
// Copy q into out[:, 0:1024] (out row stride 2048)
// ---------------------------------------------------------------------------
__global__ __launch_bounds__(256)
void copy_q_kernel(const float* __restrict__ q, float* __restrict__ out, long n4)
{
    const long idx = (long)blockIdx.x * 256 + threadIdx.x;
    if (idx >= n4) return;
    const long row = idx >> 8;
    const long c4 = idx & 255;
    *(float4*)(&out[row * 2048 + c4 * 4]) =
        *(const float4*)(&q[row * 1024 + c4 * 4]);
}

// ===========================================================================
// fp32 fallback (round-0 path) for small workspaces
// ===========================================================================
#define BM 64
#define BN 64
#define BK 16
template<int opA, int opB>
__global__ __launch_bounds__(256)
void sgemm(const float* __restrict__ A, const float* __restrict__ B,
           float* __restrict__ C,
           int M, int N, int K, int lda, int ldb, int ldc)
{
    __shared__ float As[BK][BM];
    __shared__ float Bs[BK][BN];
    const int tid = threadIdx.x;
    const int tx = tid & 15, ty = tid >> 4;
    const int bm = blockIdx.y * BM, bn = blockIdx.x * BN;
    float acc[4][4] = {};
    for (int k0 = 0; k0 < K; k0 += BK) {
        if (opA == 0) {
            const int row = tid >> 2, kq = (tid & 3) * 4;
            const float4 v = *(const float4*)(A + (long)(bm + row) * lda + (k0 + kq));
            As[kq + 0][row] = v.x; As[kq + 1][row] = v.y;
            As[kq + 2][row] = v.z; As[kq + 3][row] = v.w;
        } else {
            const int kk = tid >> 4, mq = (tid & 15) * 4;
            *(float4*)(&As[kk][mq]) =
                *(const float4*)(A + (long)(k0 + kk) * lda + (bm + mq));
        }
        if (opB == 0) {
            const int kk = tid >> 4, nq = (tid & 15) * 4;
            *(float4*)(&Bs[kk][nq]) =
                *(const float4*)(B + (long)(k0 + kk) * ldb + (bn + nq));
        } else {
            const int row = tid >> 2, kq = (tid & 3) * 4;
            const float4 v = *(const float4*)(B + (long)(bn + row) * ldb + (k0 + kq));
            Bs[kq + 0][row] = v.x; Bs[kq + 1][row] = v.y;
            Bs[kq + 2][row] = v.z; Bs[kq + 3][row] = v.w;
        }
        __syncthreads();
        #pragma unroll
        for (int kk = 0; kk < BK; ++kk) {
            const float4 a = *(const float4*)(&As[kk][ty * 4]);
            const float4 b = *(const float4*)(&Bs[kk][tx * 4]);
            const float av[4] = {a.x, a.y, a.z, a.w};
            const float bv[4] = {b.x, b.y, b.z, b.w};
            #pragma unroll
            for (int i = 0; i < 4; ++i)
                #pragma unroll
                for (int j = 0; j < 4; ++j)
                    acc[i][j] += av[i] * bv[j];
        }
        __syncthreads();
    }
    #pragma unroll
    for (int i = 0; i < 4; ++i) {
        const float4 v = make_float4(acc[i][0], acc[i][1], acc[i][2], acc[i][3]);
        *(float4*)(&C[(long)(bm + ty * 4 + i) * ldc + (bn + tx * 4)]) = v;
    }
}

__global__ __launch_bounds__(256)
void softmax_rows2048(float* __restrict__ X)
{
    float* x = X + (long)blockIdx.x * 2048;
    const int tid = threadIdx.x;
    float4 v0 = *(const float4*)(&x[tid * 4]);
    float4 v1 = *(const float4*)(&x[1024 + tid * 4]);
    float m = fmaxf(fmaxf(fmaxf(v0.x, v0.y), fmaxf(v0.z, v0.w)),
                    fmaxf(fmaxf(v1.x, v1.y), fmaxf(v1.z, v1.w)));
    m = wave_reduce_max(m);
    __shared__ float sm[4];
    __shared__ float ss[4];
    const int wid = tid >> 6;
    if ((tid & 63) == 0) sm[wid] = m;
    __syncthreads();
    m = fmaxf(fmaxf(sm[0], sm[1]), fmaxf(sm[2], sm[3]));
    v0.x = expf(v0.x - m); v0.y = expf(v0.y - m);
    v0.z = expf(v0.z - m); v0.w = expf(v0.w - m);
    v1.x = expf(v1.x - m); v1.y = expf(v1.y - m);
    v1.z = expf(v1.z - m); v1.w = expf(v1.w - m);
    float s = (v0.x + v0.y + v0.z + v0.w) + (v1.x + v1.y + v1.z + v1.w);
    s = wave_reduce_sum(s);
    if ((tid & 63) == 0) ss[wid] = s;
    __syncthreads();
    s = ss[0] + ss[1] + ss[2] + ss[3];
    const float inv = 1.0f / s;
    v0.x *= inv; v0.y *= inv; v0.z *= inv; v0.w *= inv;
    v1.x *= inv; v1.y *= inv; v1.z *= inv; v1.w *= inv;
    *(float4*)(&x[tid * 4]) = v0;
    *(float4*)(&x[1024 + tid * 4]) = v1;
}

static void fallback_fp32(const float* q, const float* k, const float* Wq,
                          const float* Wk, const float* Wv, float* out,
                          void* d_ws, hipStream_t stream)
{
    const int S = 2048, D = 1024, O = 1024, B = 8;
    float* qp = (float*)d_ws;
    float* kp = qp + (size_t)S * O;
    float* vp = kp + (size_t)S * O;
    float* attn = vp + (size_t)S * O;
    const long n4 = (long)B * S * D / 4;
    copy_q_kernel<<<dim3((n4 + 255) / 256), 256, 0, stream>>>(q, out, n4);
    const dim3 blk(256);
    const dim3 gproj(O / BN, S / BM), gattn(S / BN, S / BM), gctx(O / BN, S / BM);
    for (int b = 0; b < B; ++b) {
        const float* qb = q + (size_t)b * S * D;
        const float* kb = k + (size_t)b * S * D;
        float* outc = out + (size_t)b * S * 2048 + D;
        sgemm<0, 0><<<gproj, blk, 0, stream>>>(qb, Wq, qp, S, O, D, D, O, O);
        sgemm<0, 0><<<gproj, blk, 0, stream>>>(kb, Wk, kp, S, O, D, D, O, O);
        sgemm<0, 0><<<gproj, blk, 0, stream>>>(kb, Wv, vp, S, O, D, D, O, O);
        sgemm<0, 1><<<gattn, blk, 0, stream>>>(qp, kp, attn, S, S, O, O, O, S);
        softmax_rows2048<<<dim3(S), blk, 0, stream>>>(attn);
        sgemm<1, 0><<<gctx, blk, 0, stream>>>(attn, vp, outc, S, O, S, S, O, 2048);
    }
}

// ===========================================================================
extern "C" void kernel_launch(void* const* d_in, const int* in_sizes, int n_in,
                              void* d_out, int out_size, void* d_ws, size_t ws_size,
                              hipStream_t stream)
{
    const float* q  = (const float*)d_in[0];
    const float* k  = (const float*)d_in[1];
    const float* Wq = (const float*)d_in[2];
    const float* Wk = (const float*)d_in[3];
    const float* Wv = (const float*)d_in[4];
    float* out = (float*)d_out;

    const int B = 8, S = 2048;

    // per-group (g batches) buffer sizes in bytes
    auto need = [](int g) -> size_t {
        const size_t wpk  = 3 * (size_t)1024 * 3072 * 2;       // W packs
        const size_t pk   = (size_t)g * 2048 * 3072 * 2;       // each of 4 packs
        const size_t vpT  = (size_t)1024 * g * 2048 * 2;
        const size_t attn = (size_t)g * 2048 * 2048 * 4;
        const size_t aw   = (size_t)g * 2048 * 2048 * 2;
        return wpk + 4 * pk + vpT + attn + 2 * aw + 16 * 256;
    };
    int g = 0;
    for (int cand : {8, 4, 2, 1})
        if (need(cand) <= ws_size) { g = cand; break; }
    if (g == 0) { fallback_fp32(q, k, Wq, Wk, Wv, out, d_ws, stream); return; }

    // carve workspace
    char* p = (char*)d_ws;
    auto carve = [&](size_t bytes) {
        char* r = p;
        p += (bytes + 255) & ~(size_t)255;
        return r;
    };
    unsigned short* Wtq = (unsigned short*)carve((size_t)1024 * 3072 * 2);
    unsigned short* Wtk = (unsigned short*)carve((size_t)1024 * 3072 * 2);
    unsigned short* Wtv = (unsigned short*)carve((size_t)1024 * 3072 * 2);
    const size_t pkB = (size_t)g * 2048 * 3072 * 2;
    unsigned short* qpack   = (unsigned short*)carve(pkB);
    unsigned short* kpack   = (unsigned short*)carve(pkB);
    unsigned short* qp_pack = (unsigned short*)carve(pkB);
    unsigned short* kp_pack = (unsigned short*)carve(pkB);
    unsigned short* vpT     = (unsigned short*)carve((size_t)1024 * g * 2048 * 2);
    float*          attn    = (float*)carve((size_t)g * 2048 * 2048 * 4);
    unsigned short* attn_w  = (unsigned short*)carve((size_t)g * 2048 * 2048 * 2);
    unsigned short* attnT   = (unsigned short*)carve((size_t)g * 2048 * 2048 * 2);

    // W packs (once)
    pack_W_T<<<dim3(16, 16), 256, 0, stream>>>(Wq, Wtq);
    pack_W_T<<<dim3(16, 16), 256, 0, stream>>>(Wk, Wtk);
    pack_W_T<<<dim3(16, 16), 256, 0, stream>>>(Wv, Wtv);

    // out[:, :, 0:1024] = q
    {
        const long n4 = (long)B * S * 1024 / 4;
        copy_q_kernel<<<dim3((n4 + 255) / 256), 256, 0, stream>>>(q, out, n4);
    }

    const int Mg = g * 2048;
    const dim3 blk(256);

    for (int gi = 0; gi < B / g; ++gi) {
        const float* qg = q + (size_t)gi * Mg * 1024;
        const float* kg = k + (size_t)gi * Mg * 1024;

        const long nquads = (long)Mg * 256;
        pack_rows_A<<<dim3((nquads + 255) / 256), blk, 0, stream>>>(qg, qpack, nquads);
        pack_rows_A<<<dim3((nquads + 255) / 256), blk, 0, stream>>>(kg, kpack, nquads);

        // projections (3-term split): [Mg,3072] @ [1024,3072]^T
        const dim3 g1(1024 / 128, Mg / 128);
        gemm_bf16<CM_PACK_A><<<g1, blk, 0, stream>>>(
            qpack, Wtq, qp_pack, Mg, 1024, 3072, 3072, 3072, 0, 0, 0, 0);
        gemm_bf16<CM_PACK_B><<<g1, blk, 0, stream>>>(
            kpack, Wtk, kp_pack, Mg, 1024, 3072, 3072, 3072, 0, 0, 0, 0);
        gemm_bf16<CM_BF16T><<<g1, blk, 0, stream>>>(
            kpack, Wtv, vpT, Mg, 1024, 3072, 3072, 3072, Mg, 0, 0, 0);

        // attn = qp @ kp^T per batch (z), 3-term split, fp32 out
        const dim3 g2(2048 / 128, 2048 / 128, g);
        gemm_bf16<CM_F32><<<g2, blk, 0, stream>>>(
            qp_pack, kp_pack, attn, 2048, 2048, 3072, 3072, 3072, 2048,
            (long)2048 * 3072, (long)2048 * 3072, (long)2048 * 2048);

        // softmax rows -> bf16
        softmax_rows_bf16<<<dim3(g * 2048), blk, 0, stream>>>(attn, attn_w);

        // attn_w^T
        transpose_bf16_2048<<<dim3(32, 32, g), blk, 0, stream>>>(attn_w, attnT);

        // context = attnT @ vpT^T -> out cols 1024..2047
        float* outg = out + (size_t)gi * Mg * 2048 + 1024;
        const dim3 g3(1024 / 128, 2048 / 128, g);
        gemm_bf16<CM_F32><<<g3, blk, 0, stream>>>(
            attnT, vpT, outg, 2048, 1024, 2048, 2048, Mg, 2048,
            (long)2048 * 2048, 2048, (long)2048 * 2048);
    }
}

// Round 3
// 1106.041 us; speedup vs baseline: 3.3372x; 1.1221x over previous
//
#include <hip/hip_runtime.h>
#include <hip/hip_bf16.h>

// B=8, S=2048, D=1024, O=1024
// qp=q@Wq, kp=k@Wk, vp=k@Wv ; attn=qp@kp^T (no scale); w=softmax(attn,-1)
// context = attn_w^T @ vp ; out = concat([q, context], -1)  fp32 [B,S,2048]
//
// Split-bf16: x = hi + lo. hi*hi + hi*lo + lo*hi via ONE bf16 GEMM over K'=3K
// with A' = [hiA, hiA, loA], B' = [hiB, loB, hiB].
//
// GEMMs use the 256x256 8-phase template (T2 swizzle + T3/T4 counted vmcnt +
// T5 setprio + T1 XCD swizzle): BK=64, 8 waves (2Mx4N, 512 thr), LDS 128 KiB
// (2 tile buffers x {A 32K, B 32K}), 16 MFMA + 8 ds_read_b128 + 2
// global_load_lds per phase, vmcnt(4) once per K-tile (never 0).

typedef __attribute__((ext_vector_type(4))) float f32x4;
typedef __attribute__((ext_vector_type(8))) short bf16x8;
typedef __attribute__((ext_vector_type(8))) unsigned short u16x8;
typedef __attribute__((ext_vector_type(4))) unsigned short u16x4;

__device__ __forceinline__ unsigned short f2bf(float x) {
    union { float f; unsigned u; } u; u.f = x;
    unsigned r = u.u + 0x7fffu + ((u.u >> 16) & 1u);
    return (unsigned short)(r >> 16);
}
__device__ __forceinline__ float bf2f(unsigned short b) {
    union { unsigned u; float f; } u; u.u = ((unsigned)b) << 16;
    return u.f;
}

#define CM_F32    0
#define CM_PACK_A 1
#define CM_PACK_B 2
#define CM_BF16T  3

// Stage one 16 KiB unit (WHICH: 0=A,1=B; KS: k-half) of K-tile KT into buffer
// at byte offset BO. 2 global_load_lds x16 per thread; LDS linear in thread
// order; the XOR swizzle (slot = chunk ^ ((row ^ row>>2) & 3)) is applied by
// pre-swizzling the GLOBAL source chunk (rule #21: both-sides-or-neither).
#define STAGE(WHICH, KS, KT, BO) do { \
    const char* _gb = (WHICH) ? Bb : Ab; \
    const int _ld = (WHICH) ? ldb : lda; \
    const long _r = (WHICH) ? (long)(bn + srow0) : (long)(bm + srow0); \
    const int _k0 = (KT) * 64 + (KS) * 32 + sh8; \
    char* _dst = (char*)smem + (BO) + (WHICH) * 32768 + (KS) * 16384 + wave * 1024; \
    const char* _g0 = _gb + ((_r * _ld + _k0) << 1); \
    const char* _g1 = _gb + (((_r + 128) * _ld + _k0) << 1); \
    __builtin_amdgcn_global_load_lds((const __attribute__((address_space(1))) void*)_g0, \
        (__attribute__((address_space(3))) void*)_dst, 16, 0, 0); \
    __builtin_amdgcn_global_load_lds((const __attribute__((address_space(1))) void*)_g1, \
        (__attribute__((address_space(3))) void*)(_dst + 8192), 16, 0, 0); \
} while (0)

// One phase: quadrant (MH, KS) of current tile. ds_reads -> stage issue ->
// barrier -> (compiler lgkmcnt) -> setprio MFMA -> optional vmcnt -> barrier.
#define GPHASE(KS, MH, STAGE_CODE, VM) do { \
    bf16x8 af[4], bb[4]; \
    _Pragma("unroll") \
    for (int f = 0; f < 4; ++f) \
        af[f] = *(const bf16x8*)(smem + bufo + (KS) * 16384 + aoff + (MH) * 4096 + f * 1024); \
    _Pragma("unroll") \
    for (int n = 0; n < 4; ++n) \
        bb[n] = *(const bf16x8*)(smem + bufo + (KS) * 16384 + boff + n * 1024); \
    STAGE_CODE; \
    __builtin_amdgcn_sched_barrier(0); \
    __builtin_amdgcn_s_barrier(); \
    __builtin_amdgcn_sched_barrier(0); \
    __builtin_amdgcn_s_setprio(1); \
    _Pragma("unroll") \
    for (int f = 0; f < 4; ++f) { \
        _Pragma("unroll") \
        for (int n = 0; n < 4; ++n) \
            acc[(MH) * 4 + f][n] = __builtin_amdgcn_mfma_f32_16x16x32_bf16( \
                af[f], bb[n], acc[(MH) * 4 + f][n], 0, 0, 0); \
    } \
    __builtin_amdgcn_s_setprio(0); \
    VM; \
    __builtin_amdgcn_sched_barrier(0); \
    __builtin_amdgcn_s_barrier(); \
    __builtin_amdgcn_sched_barrier(0); \
} while (0)

template<int CMODE>
__global__ __launch_bounds__(512, 2)
void gemm256(const unsigned short* __restrict__ A,
             const unsigned short* __restrict__ B,
             void* __restrict__ Cv,
             int M, int N, int K, int lda, int ldb, int ldc,
             long az, long bz, long cz)
{
    __shared__ __align__(16) char smem[131072];

    const int z = blockIdx.z;
    const char* Ab = (const char*)(A + z * az);
    const char* Bb = (const char*)(B + z * bz);

    // XCD-aware swizzle on flattened grid.x (all launches have nwg % 8 == 0)
    const int nbx = N >> 8;
    int wg = blockIdx.x;
    const int nwg = gridDim.x;
    if ((nwg & 7) == 0) wg = (wg & 7) * (nwg >> 3) + (wg >> 3);
    const int bm = (wg / nbx) << 8;
    const int bn = (wg % nbx) << 8;

    const int tid = threadIdx.x;
    const int wave = tid >> 6;
    const int lane = tid & 63;
    const int r16 = lane & 15;
    const int half = (lane >> 4) & 3;
    const int wm = wave >> 2;      // 0..1 -> rows wm*128..+128
    const int wn = wave & 3;       // 0..3 -> cols wn*64..+64

    // swizzled ds_read slot (per-lane constant): slot = half ^ ((r16^(r16>>2))&3)
    const int sx = (r16 ^ (r16 >> 2)) & 3;
    const int slot16 = ((half ^ sx) << 4);
    const int aoff = (wm * 128 + r16) * 64 + slot16;           // + MH*4096 + f*1024
    const int boff = 32768 + (wn * 64 + r16) * 64 + slot16;    // + n*1024

    // staging per-thread constants
    const int srow0 = tid >> 2;                                // row within unit (+128 for 2nd load)
    const int sh8 = ((tid ^ (tid >> 2) ^ (tid >> 4)) & 3) * 8; // pre-swizzled k-chunk (elements)

    f32x4 acc[8][4];
    #pragma unroll
    for (int m = 0; m < 8; ++m)
        #pragma unroll
        for (int n = 0; n < 4; ++n)
            acc[m][n] = f32x4{0.f, 0.f, 0.f, 0.f};

    const int nt = K >> 6;   // K-tiles of 64

    // prologue: T0 fully, T1.{A.k0, B.k0}; wait all of T0 (allow T1's 4 loads)
    {
        const int t1p = (nt > 1) ? 1 : 0;
        STAGE(0, 0, 0, 0);
        STAGE(1, 0, 0, 0);
        STAGE(0, 1, 0, 0);
        STAGE(1, 1, 0, 0);
        STAGE(0, 0, t1p, 65536);
        STAGE(1, 0, t1p, 65536);
        asm volatile("s_waitcnt vmcnt(4)" ::: "memory");
        __builtin_amdgcn_sched_barrier(0);
        __builtin_amdgcn_s_barrier();
        __builtin_amdgcn_sched_barrier(0);
    }

    for (int t = 0; t < nt; ++t) {
        const int bufo = (t & 1) << 16;
        const int nbo = bufo ^ 65536;
        const int t1 = (t + 1 < nt) ? t + 1 : nt - 1;
        const int t2 = (t + 2 < nt) ? t + 2 : nt - 1;
        // phases: (ks0,mh0) (ks0,mh1) (ks1,mh0) (ks1,mh1)
        // k0 units of current tile retire after phase 1 -> stage next-even
        // tile's k0 units at phases 2,3; k1 units of buf^1 retired last tile
        // -> stage next tile's k1 units at phases 0,1.
        GPHASE(0, 0, STAGE(0, 1, t1, nbo), );
        GPHASE(0, 1, STAGE(1, 1, t1, nbo), );
        GPHASE(1, 0, STAGE(0, 0, t2, bufo), );
        GPHASE(1, 1, STAGE(1, 0, t2, bufo),
               asm volatile("s_waitcnt vmcnt(4)" ::: "memory"));
    }

    // ---- epilogue: D frag mapping col=lane&15, row=(lane>>4)*4+r ----
    #pragma unroll
    for (int m = 0; m < 8; ++m) {
        #pragma unroll
        for (int n = 0; n < 4; ++n) {
            const int row0 = bm + wm * 128 + m * 16 + half * 4;
            const int col = bn + wn * 64 + n * 16 + r16;
            if (CMODE == CM_F32) {
                float* C = (float*)Cv + z * cz;
                #pragma unroll
                for (int r = 0; r < 4; ++r)
                    C[(long)(row0 + r) * ldc + col] = acc[m][n][r];
            } else if (CMODE == CM_PACK_A || CMODE == CM_PACK_B) {
                unsigned short* C = (unsigned short*)Cv + z * cz;
                #pragma unroll
                for (int r = 0; r < 4; ++r) {
                    const float v = acc[m][n][r];
                    const unsigned short h = f2bf(v);
                    const unsigned short l = f2bf(v - bf2f(h));
                    const long base = (long)(row0 + r) * (3LL * N) + col;
                    if (CMODE == CM_PACK_A) {
                        C[base] = h; C[base + N] = h; C[base + 2 * N] = l;
                    } else {
                        C[base] = h; C[base + N] = l; C[base + 2 * N] = h;
                    }
                }
            } else { // CM_BF16T
                unsigned short* C = (unsigned short*)Cv + z * cz;
                u16x4 v;
                #pragma unroll
                for (int r = 0; r < 4; ++r) v[r] = f2bf(acc[m][n][r]);
                *(u16x4*)(C + (long)col * ldc + row0) = v;
            }
        }
    }
}

// ---------------------------------------------------------------------------
// Pack fp32 rows [R,1024] -> bf16 [R,3072] in A-order [hi,hi,lo]
// ---------------------------------------------------------------------------
__global__ __launch_bounds__(256)
void pack_rows_A(const float* __restrict__ in, unsigned short* __restrict__ out,
                 long nquads)
{
    const long i = (long)blockIdx.x * 256 + threadIdx.x;
    if (i >= nquads) return;
    const long row = i >> 8;
    const int c = (int)(i & 255) * 4;
    const float4 v = *(const float4*)(in + row * 1024 + c);
    const float vv[4] = {v.x, v.y, v.z, v.w};
    u16x4 h, l;
    #pragma unroll
    for (int j = 0; j < 4; ++j) {
        h[j] = f2bf(vv[j]);
        l[j] = f2bf(vv[j] - bf2f(h[j]));
    }
    unsigned short* o = out + row * 3072 + c;
    *(u16x4*)(o) = h;
    *(u16x4*)(o + 1024) = h;
    *(u16x4*)(o + 2048) = l;
}

// ---------------------------------------------------------------------------
// W [1024(d),1024(o)] fp32 -> Wt [1024(o),3072] bf16 in B-order [hi,lo,hi]
// ---------------------------------------------------------------------------
__global__ __launch_bounds__(256)
void pack_W_T(const float* __restrict__ W, unsigned short* __restrict__ Wt)
{
    __shared__ float tile[64][65];
    const int d0 = blockIdx.y * 64, o0 = blockIdx.x * 64;
    const int t = threadIdx.x;
    const int rr = t >> 4, c4 = (t & 15) * 4;
    #pragma unroll
    for (int it = 0; it < 4; ++it) {
        const int r = rr + it * 16;
        const float4 v = *(const float4*)(W + (long)(d0 + r) * 1024 + o0 + c4);
        tile[r][c4] = v.x; tile[r][c4 + 1] = v.y;
        tile[r][c4 + 2] = v.z; tile[r][c4 + 3] = v.w;
    }
    __syncthreads();
    #pragma unroll
    for (int it = 0; it < 4; ++it) {
        const int orow = rr + it * 16;
        u16x4 h, l;
        #pragma unroll
        for (int j = 0; j < 4; ++j) {
            const float x = tile[c4 + j][orow];
            h[j] = f2bf(x);
            l[j] = f2bf(x - bf2f(h[j]));
        }
        unsigned short* o = Wt + (long)(o0 + orow) * 3072 + d0 + c4;
        *(u16x4*)(o) = h;
        *(u16x4*)(o + 1024) = l;
        *(u16x4*)(o + 2048) = h;
    }
}

// ---------------------------------------------------------------------------
__device__ __forceinline__ float wave_reduce_max(float v) {
    #pragma unroll
    for (int off = 1; off < 64; off <<= 1)
        v = fmaxf(v, __shfl_xor(v, off, 64));
    return v;
}
__device__ __forceinline__ float wave_reduce_sum(float v) {
    #pragma unroll
    for (int off = 1; off < 64; off <<= 1)
        v += __shfl_xor(v, off, 64);
    return v;
}

__global__ __launch_bounds__(256)
void softmax_rows_bf16(const float* __restrict__ X, unsigned short* __restrict__ Y)
{
    const float* x = X + (long)blockIdx.x * 2048;
    unsigned short* y = Y + (long)blockIdx.x * 2048;
    const int tid = threadIdx.x;

    float4 v0 = *(const float4*)(x + tid * 4);
    float4 v1 = *(const float4*)(x + 1024 + tid * 4);

    float m = fmaxf(fmaxf(fmaxf(v0.x, v0.y), fmaxf(v0.z, v0.w)),
                    fmaxf(fmaxf(v1.x, v1.y), fmaxf(v1.z, v1.w)));
    m = wave_reduce_max(m);

    __shared__ float sm[4];
    __shared__ float ss[4];
    const int wid = tid >> 6;
    if ((tid & 63) == 0) sm[wid] = m;
    __syncthreads();
    m = fmaxf(fmaxf(sm[0], sm[1]), fmaxf(sm[2], sm[3]));

    v0.x = expf(v0.x - m); v0.y = expf(v0.y - m);
    v0.z = expf(v0.z - m); v0.w = expf(v0.w - m);
    v1.x = expf(v1.x - m); v1.y = expf(v1.y - m);
    v1.z = expf(v1.z - m); v1.w = expf(v1.w - m);

    float s = (v0.x + v0.y + v0.z + v0.w) + (v1.x + v1.y + v1.z + v1.w);
    s = wave_reduce_sum(s);
    if ((tid & 63) == 0) ss[wid] = s;
    __syncthreads();
    s = ss[0] + ss[1] + ss[2] + ss[3];

    const float inv = 1.0f / s;
    u16x4 o0, o1;
    o0[0] = f2bf(v0.x * inv); o0[1] = f2bf(v0.y * inv);
    o0[2] = f2bf(v0.z * inv); o0[3] = f2bf(v0.w * inv);
    o1[0] = f2bf(v1.x * inv); o1[1] = f2bf(v1.y * inv);
    o1[2] = f2bf(v1.z * inv); o1[3] = f2bf(v1.w * inv);
    *(u16x4*)(y + tid * 4) = o0;
    *(u16x4*)(y + 1024 + tid * 4) = o1;
}

// ---------------------------------------------------------------------------
__global__ __launch_bounds__(256)
void transpose_bf16_2048(const unsigned short* __restrict__ in,
                         unsigned short* __restrict__ out)
{
    __shared__ unsigned short tile[64][66];
    const long zoff = (long)blockIdx.z * 2048 * 2048;
    const int r0 = blockIdx.y * 64, c0 = blockIdx.x * 64;
    const int t = threadIdx.x;
    const int rr = t >> 3, seg = (t & 7) * 8;
    #pragma unroll
    for (int it = 0; it < 2; ++it) {
        const int r = rr + it * 32;
        u16x8 v = *(const u16x8*)(in + zoff + (long)(r0 + r) * 2048 + c0 + seg);
        #pragma unroll
        for (int j = 0; j < 8; ++j) tile[r][seg + j] = v[j];
    }
    __syncthreads();
    #pragma unroll
    for (int it = 0; it < 2; ++it) {
        const int r = rr + it * 32;
        u16x8 v;
        #pragma unroll
        for (int j = 0; j < 8; ++j) v[j] = tile[seg + j][r];
        *(u16x8*)(out + zoff + (long)(c0 + r) * 2048 + r0 + seg) = v;
    }
}

// ---------------------------------------------------------------------------
__global__ __launch_bounds__(256)
void copy_q_kernel(const float* __restrict__ q, float* __restrict__ out, long n4)
{
    const long idx = (long)blockIdx.x * 256 + threadIdx.x;
    if (idx >= n4) return;
    const long row = idx >> 8;
    const long c4 = idx & 255;
    *(float4*)(&out[row * 2048 + c4 * 4]) =
        *(const float4*)(&q[row * 1024 + c4 * 4]);
}

// ===========================================================================
// fp32 fallback for small workspaces
// ===========================================================================
#define BM 64
#define BN 64
#define BKF 16
template<int opA, int opB>
__global__ __launch_bounds__(256)
void sgemm(const float* __restrict__ A, const float* __restrict__ B,
           float* __restrict__ C,
           int M, int N, int K, int lda, int ldb, int ldc)
{
    __shared__ float As[BKF][BM];
    __shared__ float Bs[BKF][BN];
    const int tid = threadIdx.x;
    const int tx = tid & 15, ty = tid >> 4;
    const int bm = blockIdx.y * BM, bn = blockIdx.x * BN;
    float acc[4][4] = {};
    for (int k0 = 0; k0 < K; k0 += BKF) {
        if (opA == 0) {
            const int row = tid >> 2, kq = (tid & 3) * 4;
            const float4 v = *(const float4*)(A + (long)(bm + row) * lda + (k0 + kq));
            As[kq + 0][row] = v.x; As[kq + 1][row] = v.y;
            As[kq + 2][row] = v.z; As[kq + 3][row] = v.w;
        } else {
            const int kk = tid >> 4, mq = (tid & 15) * 4;
            *(float4*)(&As[kk][mq]) =
                *(const float4*)(A + (long)(k0 + kk) * lda + (bm + mq));
        }
        if (opB == 0) {
            const int kk = tid >> 4, nq = (tid & 15) * 4;
            *(float4*)(&Bs[kk][nq]) =
                *(const float4*)(B + (long)(k0 + kk) * ldb + (bn + nq));
        } else {
            const int row = tid >> 2, kq = (tid & 3) * 4;
            const float4 v = *(const float4*)(B + (long)(bn + row) * ldb + (k0 + kq));
            Bs[kq + 0][row] = v.x; Bs[kq + 1][row] = v.y;
            Bs[kq + 2][row] = v.z; Bs[kq + 3][row] = v.w;
        }
        __syncthreads();
        #pragma unroll
        for (int kk = 0; kk < BKF; ++kk) {
            const float4 a = *(const float4*)(&As[kk][ty * 4]);
            const float4 b = *(const float4*)(&Bs[kk][tx * 4]);
            const float av[4] = {a.x, a.y, a.z, a.w};
            const float bv[4] = {b.x, b.y, b.z, b.w};
            #pragma unroll
            for (int i = 0; i < 4; ++i)
                #pragma unroll
                for (int j = 0; j < 4; ++j)
                    acc[i][j] += av[i] * bv[j];
        }
        __syncthreads();
    }
    #pragma unroll
    for (int i = 0; i < 4; ++i) {
        const float4 v = make_float4(acc[i][0], acc[i][1], acc[i][2], acc[i][3]);
        *(float4*)(&C[(long)(bm + ty * 4 + i) * ldc + (bn + tx * 4)]) = v;
    }
}

__global__ __launch_bounds__(256)
void softmax_rows2048(float* __restrict__ X)
{
    float* x = X + (long)blockIdx.x * 2048;
    const int tid = threadIdx.x;
    float4 v0 = *(const float4*)(&x[tid * 4]);
    float4 v1 = *(const float4*)(&x[1024 + tid * 4]);
    float m = fmaxf(fmaxf(fmaxf(v0.x, v0.y), fmaxf(v0.z, v0.w)),
                    fmaxf(fmaxf(v1.x, v1.y), fmaxf(v1.z, v1.w)));
    m = wave_reduce_max(m);
    __shared__ float sm[4];
    __shared__ float ss[4];
    const int wid = tid >> 6;
    if ((tid & 63) == 0) sm[wid] = m;
    __syncthreads();
    m = fmaxf(fmaxf(sm[0], sm[1]), fmaxf(sm[2], sm[3]));
    v0.x = expf(v0.x - m); v0.y = expf(v0.y - m);
    v0.z = expf(v0.z - m); v0.w = expf(v0.w - m);
    v1.x = expf(v1.x - m); v1.y = expf(v1.y - m);
    v1.z = expf(v1.z - m); v1.w = expf(v1.w - m);
    float s = (v0.x + v0.y + v0.z + v0.w) + (v1.x + v1.y + v1.z + v1.w);
    s = wave_reduce_sum(s);
    if ((tid & 63) == 0) ss[wid] = s;
    __syncthreads();
    s = ss[0] + ss[1] + ss[2] + ss[3];
    const float inv = 1.0f / s;
    v0.x *= inv; v0.y *= inv; v0.z *= inv; v0.w *= inv;
    v1.x *= inv; v1.y *= inv; v1.z *= inv; v1.w *= inv;
    *(float4*)(&x[tid * 4]) = v0;
    *(float4*)(&x[1024 + tid * 4]) = v1;
}

static void fallback_fp32(const float* q, const float* k, const float* Wq,
                          const float* Wk, const float* Wv, float* out,
                          void* d_ws, hipStream_t stream)
{
    const int S = 2048, D = 1024, O = 1024, B = 8;
    float* qp = (float*)d_ws;
    float* kp = qp + (size_t)S * O;
    float* vp = kp + (size_t)S * O;
    float* attn = vp + (size_t)S * O;
    const long n4 = (long)B * S * D / 4;
    copy_q_kernel<<<dim3((n4 + 255) / 256), 256, 0, stream>>>(q, out, n4);
    const dim3 blk(256);
    const dim3 gproj(O / BN, S / BM), gattn(S / BN, S / BM), gctx(O / BN, S / BM);
    for (int b = 0; b < B; ++b) {
        const float* qb = q + (size_t)b * S * D;
        const float* kb = k + (size_t)b * S * D;
        float* outc = out + (size_t)b * S * 2048 + D;
        sgemm<0, 0><<<gproj, blk, 0, stream>>>(qb, Wq, qp, S, O, D, D, O, O);
        sgemm<0, 0><<<gproj, blk, 0, stream>>>(kb, Wk, kp, S, O, D, D, O, O);
        sgemm<0, 0><<<gproj, blk, 0, stream>>>(kb, Wv, vp, S, O, D, D, O, O);
        sgemm<0, 1><<<gattn, blk, 0, stream>>>(qp, kp, attn, S, S, O, O, O, S);
        softmax_rows2048<<<dim3(S), blk, 0, stream>>>(attn);
        sgemm<1, 0><<<gctx, blk, 0, stream>>>(attn, vp, outc, S, O, S, S, O, 2048);
    }
}

// ===========================================================================
extern "C" void kernel_launch(void* const* d_in, const int* in_sizes, int n_in,
                              void* d_out, int out_size, void* d_ws, size_t ws_size,
                              hipStream_t stream)
{
    const float* q  = (const float*)d_in[0];
    const float* k  = (const float*)d_in[1];
    const float* Wq = (const float*)d_in[2];
    const float* Wk = (const float*)d_in[3];
    const float* Wv = (const float*)d_in[4];
    float* out = (float*)d_out;

    const int B = 8, S = 2048;

    auto need = [](int g) -> size_t {
        const size_t wpk  = 3 * (size_t)1024 * 3072 * 2;
        const size_t pk   = (size_t)g * 2048 * 3072 * 2;
        const size_t vpT  = (size_t)1024 * g * 2048 * 2;
        const size_t attn = (size_t)g * 2048 * 2048 * 4;
        const size_t aw   = (size_t)g * 2048 * 2048 * 2;
        return wpk + 4 * pk + vpT + attn + 2 * aw + 16 * 256;
    };
    int g = 0;
    for (int cand : {8, 4, 2, 1})
        if (need(cand) <= ws_size) { g = cand; break; }
    if (g == 0) { fallback_fp32(q, k, Wq, Wk, Wv, out, d_ws, stream); return; }

    char* p = (char*)d_ws;
    auto carve = [&](size_t bytes) {
        char* r = p;
        p += (bytes + 255) & ~(size_t)255;
        return r;
    };
    unsigned short* Wtq = (unsigned short*)carve((size_t)1024 * 3072 * 2);
    unsigned short* Wtk = (unsigned short*)carve((size_t)1024 * 3072 * 2);
    unsigned short* Wtv = (unsigned short*)carve((size_t)1024 * 3072 * 2);
    const size_t pkB = (size_t)g * 2048 * 3072 * 2;
    unsigned short* qpack   = (unsigned short*)carve(pkB);
    unsigned short* kpack   = (unsigned short*)carve(pkB);
    unsigned short* qp_pack = (unsigned short*)carve(pkB);
    unsigned short* kp_pack = (unsigned short*)carve(pkB);
    unsigned short* vpT     = (unsigned short*)carve((size_t)1024 * g * 2048 * 2);
    float*          attn    = (float*)carve((size_t)g * 2048 * 2048 * 4);
    unsigned short* attn_w  = (unsigned short*)carve((size_t)g * 2048 * 2048 * 2);
    unsigned short* attnT   = (unsigned short*)carve((size_t)g * 2048 * 2048 * 2);

    pack_W_T<<<dim3(16, 16), 256, 0, stream>>>(Wq, Wtq);
    pack_W_T<<<dim3(16, 16), 256, 0, stream>>>(Wk, Wtk);
    pack_W_T<<<dim3(16, 16), 256, 0, stream>>>(Wv, Wtv);

    {
        const long n4 = (long)B * S * 1024 / 4;
        copy_q_kernel<<<dim3((n4 + 255) / 256), 256, 0, stream>>>(q, out, n4);
    }

    const int Mg = g * 2048;
    const dim3 blk(256);
    const dim3 blk512(512);

    for (int gi = 0; gi < B / g; ++gi) {
        const float* qg = q + (size_t)gi * Mg * 1024;
        const float* kg = k + (size_t)gi * Mg * 1024;

        const long nquads = (long)Mg * 256;
        pack_rows_A<<<dim3((nquads + 255) / 256), blk, 0, stream>>>(qg, qpack, nquads);
        pack_rows_A<<<dim3((nquads + 255) / 256), blk, 0, stream>>>(kg, kpack, nquads);

        // projections: [Mg,3072] @ [1024,3072]^T, 256^2 tiles
        const dim3 g1((1024 / 256) * (Mg / 256), 1, 1);
        gemm256<CM_PACK_A><<<g1, blk512, 0, stream>>>(
            qpack, Wtq, qp_pack, Mg, 1024, 3072, 3072, 3072, 0, 0, 0, 0);
        gemm256<CM_PACK_B><<<g1, blk512, 0, stream>>>(
            kpack, Wtk, kp_pack, Mg, 1024, 3072, 3072, 3072, 0, 0, 0, 0);
        gemm256<CM_BF16T><<<g1, blk512, 0, stream>>>(
            kpack, Wtv, vpT, Mg, 1024, 3072, 3072, 3072, Mg, 0, 0, 0);

        // attn = qp @ kp^T per z, fp32 out
        const dim3 g2((2048 / 256) * (2048 / 256), 1, g);
        gemm256<CM_F32><<<g2, blk512, 0, stream>>>(
            qp_pack, kp_pack, attn, 2048, 2048, 3072, 3072, 3072, 2048,
            (long)2048 * 3072, (long)2048 * 3072, (long)2048 * 2048);

        softmax_rows_bf16<<<dim3(g * 2048), blk, 0, stream>>>(attn, attn_w);

        transpose_bf16_2048<<<dim3(32, 32, g), blk, 0, stream>>>(attn_w, attnT);

        // context = attnT @ vpT^T -> out cols 1024..2047
        float* outg = out + (size_t)gi * Mg * 2048 + 1024;
        const dim3 g3((1024 / 256) * (2048 / 256), 1, g);
        gemm256<CM_F32><<<g3, blk512, 0, stream>>>(
            attnT, vpT, outg, 2048, 1024, 2048, 2048, Mg, 2048,
            (long)2048 * 2048, 2048, (long)2048 * 2048);
    }
}

// Round 4
// 551.974 us; speedup vs baseline: 6.6870x; 2.0038x over previous
//
#include <hip/hip_runtime.h>
#include <hip/hip_bf16.h>

// B=8, S=2048, D=1024, O=1024
// qp=q@Wq, kp=k@Wk, vp=k@Wv ; attn=qp@kp^T (no scale); w=softmax(attn,-1)
// context = attn_w^T @ vp ; out = concat([q, context], -1)  fp32 [B,S,2048]
//
// fp16 2-term split: x = hi + lo (fp16). One-sided: [hiA,loA]@[hiB,hiB]
// computes x_A*hi_B exactly-ish (err = x_A*lo_B ~ 2^-12 rel) over K'=2K.
// QK^T is computed TRANSPOSED (attnT = kp @ qp^T) so softmax axis (kk) is the
// M axis; per-block column partials (max, sum-exp) are fused into the GEMM
// epilogue; a merge + one normalize pass writes fp16 attnT_w; PV consumes it
// directly (no transpose kernel).

typedef __attribute__((ext_vector_type(4))) float f32x4;
typedef _Float16 f16;
typedef __attribute__((ext_vector_type(8))) _Float16 f16x8;
typedef __attribute__((ext_vector_type(4))) _Float16 f16x4;

#define LOG2E 1.4426950408889634f

#define CM_F32     0
#define CM_PACK_HH 1
#define CM_PACK_HL 2
#define CM_F16T    3
#define CM_ATTN    4

// Stage one 16 KiB unit (WHICH: 0=A,1=B; KS: k-half) of K-tile KT into buffer
// at byte offset BO. LDS dst linear in tid; XOR swizzle applied by
// pre-swizzling the GLOBAL source k-chunk (both-sides-or-neither).
#define STAGE(WHICH, KS, KT, BO) do { \
    const char* _gb = (WHICH) ? Bb : Ab; \
    const int _ld = (WHICH) ? ldb : lda; \
    const long _r = (WHICH) ? (long)(bn + srow0) : (long)(bm + srow0); \
    const int _k0 = (KT) * 64 + (KS) * 32 + sh8; \
    char* _dst = (char*)smem + (BO) + (WHICH) * 32768 + (KS) * 16384 + wave * 1024; \
    const char* _g0 = _gb + ((_r * _ld + _k0) << 1); \
    const char* _g1 = _gb + (((_r + 128) * _ld + _k0) << 1); \
    __builtin_amdgcn_global_load_lds((const __attribute__((address_space(1))) void*)_g0, \
        (__attribute__((address_space(3))) void*)_dst, 16, 0, 0); \
    __builtin_amdgcn_global_load_lds((const __attribute__((address_space(1))) void*)_g1, \
        (__attribute__((address_space(3))) void*)(_dst + 8192), 16, 0, 0); \
} while (0)

// One phase: quadrant (KS, MH). B-frags loaded only when LOADB (reused across
// MH). ds_reads -> stage issue -> barrier -> lgkmcnt (compiler) -> MFMA.
#define GPHASE(KS, MH, LOADB, STAGE_CODE, VM) do { \
    f16x8 af[4]; \
    _Pragma("unroll") \
    for (int f = 0; f < 4; ++f) \
        af[f] = *(const f16x8*)(smem + bufo + (KS) * 16384 + aoff + (MH) * 4096 + f * 1024); \
    if (LOADB) { \
        _Pragma("unroll") \
        for (int n = 0; n < 4; ++n) \
            bb[n] = *(const f16x8*)(smem + bufo + (KS) * 16384 + boff + n * 1024); \
    } \
    STAGE_CODE; \
    __builtin_amdgcn_sched_barrier(0); \
    __builtin_amdgcn_s_barrier(); \
    __builtin_amdgcn_sched_barrier(0); \
    __builtin_amdgcn_s_setprio(1); \
    _Pragma("unroll") \
    for (int f = 0; f < 4; ++f) { \
        _Pragma("unroll") \
        for (int n = 0; n < 4; ++n) \
            acc[(MH) * 4 + f][n] = __builtin_amdgcn_mfma_f32_16x16x32_f16( \
                af[f], bb[n], acc[(MH) * 4 + f][n], 0, 0, 0); \
    } \
    __builtin_amdgcn_s_setprio(0); \
    VM; \
    __builtin_amdgcn_sched_barrier(0); \
    __builtin_amdgcn_s_barrier(); \
    __builtin_amdgcn_sched_barrier(0); \
} while (0)

template<int CMODE>
__global__ __launch_bounds__(512, 2)
void gemm256(const f16* __restrict__ A, const f16* __restrict__ B,
             void* __restrict__ Cv,
             int M, int N, int K, int lda, int ldb, int ldc,
             long az, long bz, long cz,
             float* __restrict__ pm, float* __restrict__ ps)
{
    __shared__ __align__(16) char smem[131072];

    const int z = blockIdx.z;
    const char* Ab = (const char*)(A + z * az);
    const char* Bb = (const char*)(B + z * bz);

    // XCD-aware swizzle (all launches have nwg % 8 == 0)
    const int nbx = N >> 8;
    int wg = blockIdx.x;
    const int nwg = gridDim.x;
    if ((nwg & 7) == 0) wg = (wg & 7) * (nwg >> 3) + (wg >> 3);
    const int bm = (wg / nbx) << 8;
    const int bn = (wg % nbx) << 8;

    const int tid = threadIdx.x;
    const int wave = tid >> 6;
    const int lane = tid & 63;
    const int r16 = lane & 15;
    const int half = (lane >> 4) & 3;
    const int wm = wave >> 2;      // 0..1 -> rows wm*128..+128
    const int wn = wave & 3;       // 0..3 -> cols wn*64..+64

    // swizzled ds_read slot: slot = half ^ ((r16 ^ (r16>>2)) & 3)
    const int sx = (r16 ^ (r16 >> 2)) & 3;
    const int slot16 = ((half ^ sx) << 4);
    const int aoff = (wm * 128 + r16) * 64 + slot16;
    const int boff = 32768 + (wn * 64 + r16) * 64 + slot16;

    const int srow0 = tid >> 2;
    const int sh8 = ((tid ^ (tid >> 2) ^ (tid >> 4)) & 3) * 8;

    f32x4 acc[8][4];
    #pragma unroll
    for (int m = 0; m < 8; ++m)
        #pragma unroll
        for (int n = 0; n < 4; ++n)
            acc[m][n] = f32x4{0.f, 0.f, 0.f, 0.f};

    f16x8 bb[4];

    const int nt = K >> 6;

    {
        const int t1p = (nt > 1) ? 1 : 0;
        STAGE(0, 0, 0, 0);
        STAGE(1, 0, 0, 0);
        STAGE(0, 1, 0, 0);
        STAGE(1, 1, 0, 0);
        STAGE(0, 0, t1p, 65536);
        STAGE(1, 0, t1p, 65536);
        asm volatile("s_waitcnt vmcnt(4)" ::: "memory");
        __builtin_amdgcn_sched_barrier(0);
        __builtin_amdgcn_s_barrier();
        __builtin_amdgcn_sched_barrier(0);
    }

    for (int t = 0; t < nt; ++t) {
        const int bufo = (t & 1) << 16;
        const int nbo = bufo ^ 65536;
        const int t1 = (t + 1 < nt) ? t + 1 : nt - 1;
        const int t2 = (t + 2 < nt) ? t + 2 : nt - 1;
        GPHASE(0, 0, 1, STAGE(0, 1, t1, nbo), );
        GPHASE(0, 1, 0, STAGE(1, 1, t1, nbo), );
        GPHASE(1, 0, 1, STAGE(0, 0, t2, bufo), );
        GPHASE(1, 1, 0, STAGE(1, 0, t2, bufo),
               asm volatile("s_waitcnt vmcnt(4)" ::: "memory"));
    }
    // drain pending LDS-DMA before the workgroup can exit
    asm volatile("s_waitcnt vmcnt(0)" ::: "memory");

    // ---- epilogue: D frag mapping col=lane&15, row=(lane>>4)*4+r ----
    if (CMODE == CM_ATTN) {
        float* C = (float*)Cv + z * cz;
        #pragma unroll
        for (int m = 0; m < 8; ++m)
            #pragma unroll
            for (int n = 0; n < 4; ++n) {
                const int row0 = bm + wm * 128 + m * 16 + half * 4;
                const int col = bn + wn * 64 + n * 16 + r16;
                #pragma unroll
                for (int r = 0; r < 4; ++r)
                    C[(long)(row0 + r) * ldc + col] = acc[m][n][r];
            }
        // per-block column (softmax-axis) partials over 256 rows
        float cm[4], cs[4];
        #pragma unroll
        for (int n = 0; n < 4; ++n) {
            float mx = -3.4e38f;
            #pragma unroll
            for (int m = 0; m < 8; ++m)
                #pragma unroll
                for (int r = 0; r < 4; ++r)
                    mx = fmaxf(mx, acc[m][n][r]);
            float sm = 0.f;
            #pragma unroll
            for (int m = 0; m < 8; ++m)
                #pragma unroll
                for (int r = 0; r < 4; ++r)
                    sm += exp2f((acc[m][n][r] - mx) * LOG2E);
            #pragma unroll
            for (int off = 16; off < 64; off <<= 1) {
                const float mo = __shfl_xor(mx, off, 64);
                const float so = __shfl_xor(sm, off, 64);
                const float mn2 = fmaxf(mx, mo);
                sm = sm * exp2f((mx - mn2) * LOG2E) + so * exp2f((mo - mn2) * LOG2E);
                mx = mn2;
            }
            cm[n] = mx; cs[n] = sm;
        }
        float2* part = (float2*)smem;   // [8 waves][4 n][16]
        if (lane < 16) {
            #pragma unroll
            for (int n = 0; n < 4; ++n)
                part[(wave * 4 + n) * 16 + r16] = make_float2(cm[n], cs[n]);
        }
        __syncthreads();
        if (wm == 0 && lane < 16) {
            #pragma unroll
            for (int n = 0; n < 4; ++n) {
                const float2 a = part[(wave * 4 + n) * 16 + r16];
                const float2 b2 = part[((wave + 4) * 4 + n) * 16 + r16];
                const float mn2 = fmaxf(a.x, b2.x);
                const float s = a.y * exp2f((a.x - mn2) * LOG2E) +
                                b2.y * exp2f((b2.x - mn2) * LOG2E);
                const long pidx = ((long)z * 8 + (bm >> 8)) * N +
                                  (bn + wn * 64 + n * 16 + r16);
                pm[pidx] = mn2;
                ps[pidx] = s;
            }
        }
        return;
    }

    #pragma unroll
    for (int m = 0; m < 8; ++m) {
        #pragma unroll
        for (int n = 0; n < 4; ++n) {
            const int row0 = bm + wm * 128 + m * 16 + half * 4;
            const int col = bn + wn * 64 + n * 16 + r16;
            if (CMODE == CM_F32) {
                float* C = (float*)Cv + z * cz;
                #pragma unroll
                for (int r = 0; r < 4; ++r)
                    C[(long)(row0 + r) * ldc + col] = acc[m][n][r];
            } else if (CMODE == CM_PACK_HH || CMODE == CM_PACK_HL) {
                f16* C = (f16*)Cv + z * cz;
                #pragma unroll
                for (int r = 0; r < 4; ++r) {
                    const float v = acc[m][n][r];
                    const f16 h = (f16)v;
                    const long base = (long)(row0 + r) * (2LL * N) + col;
                    C[base] = h;
                    C[base + N] = (CMODE == CM_PACK_HH) ? h : (f16)(v - (float)h);
                }
            } else { // CM_F16T: C^T[col][row0..row0+3]
                f16* C = (f16*)Cv + z * cz;
                f16x4 v;
                #pragma unroll
                for (int r = 0; r < 4; ++r) v[r] = (f16)acc[m][n][r];
                *(f16x4*)(C + (long)col * ldc + row0) = v;
            }
        }
    }
}

// ---------------------------------------------------------------------------
// fp32 rows [R,1024] -> f16 [R,2048] as [hi | lo]
// ---------------------------------------------------------------------------
__global__ __launch_bounds__(256)
void pack_rows_HL(const float* __restrict__ in, f16* __restrict__ out, long nquads)
{
    const long i = (long)blockIdx.x * 256 + threadIdx.x;
    if (i >= nquads) return;
    const long row = i >> 8;
    const int c = (int)(i & 255) * 4;
    const float4 v = *(const float4*)(in + row * 1024 + c);
    const float vv[4] = {v.x, v.y, v.z, v.w};
    f16x4 h, l;
    #pragma unroll
    for (int j = 0; j < 4; ++j) {
        h[j] = (f16)vv[j];
        l[j] = (f16)(vv[j] - (float)h[j]);
    }
    f16* o = out + row * 2048 + c;
    *(f16x4*)o = h;
    *(f16x4*)(o + 1024) = l;
}

// ---------------------------------------------------------------------------
// W [1024 d][1024 o] fp32 -> Wt [1024 o][2048] = [hi | hi] (DUP2=1)
//                        or Wt [1024 o][1024] = [hi]       (DUP2=0)
// ---------------------------------------------------------------------------
template<int DUP2>
__global__ __launch_bounds__(256)
void pack_W_T(const float* __restrict__ W, f16* __restrict__ Wt)
{
    __shared__ float tile[64][65];
    const int d0 = blockIdx.y * 64, o0 = blockIdx.x * 64;
    const int t = threadIdx.x;
    const int rr = t >> 4, c4 = (t & 15) * 4;
    #pragma unroll
    for (int it = 0; it < 4; ++it) {
        const int r = rr + it * 16;
        const float4 v = *(const float4*)(W + (long)(d0 + r) * 1024 + o0 + c4);
        tile[r][c4] = v.x; tile[r][c4 + 1] = v.y;
        tile[r][c4 + 2] = v.z; tile[r][c4 + 3] = v.w;
    }
    __syncthreads();
    #pragma unroll
    for (int it = 0; it < 4; ++it) {
        const int orow = rr + it * 16;
        f16x4 h;
        #pragma unroll
        for (int j = 0; j < 4; ++j) h[j] = (f16)tile[c4 + j][orow];
        f16* o = Wt + (long)(o0 + orow) * (DUP2 ? 2048 : 1024) + d0 + c4;
        *(f16x4*)o = h;
        if (DUP2) *(f16x4*)(o + 1024) = h;
    }
}

// ---------------------------------------------------------------------------
// merge per-block partials -> L2[z,q] = m*log2e + log2(s)
// ---------------------------------------------------------------------------
__global__ __launch_bounds__(256)
void softmax_merge(const float* __restrict__ pm, const float* __restrict__ ps,
                   float* __restrict__ L2, int nq)
{
    const int idx = blockIdx.x * 256 + threadIdx.x;
    if (idx >= nq) return;
    const int z = idx >> 11, q = idx & 2047;
    const float* pmz = pm + (long)z * 8 * 2048 + q;
    const float* psz = ps + (long)z * 8 * 2048 + q;
    float m = -3.4e38f;
    #pragma unroll
    for (int mb = 0; mb < 8; ++mb) m = fmaxf(m, pmz[mb * 2048]);
    float s = 0.f;
    #pragma unroll
    for (int mb = 0; mb < 8; ++mb)
        s += psz[mb * 2048] * exp2f((pmz[mb * 2048] - m) * LOG2E);
    L2[idx] = m * LOG2E + log2f(s);
}

// ---------------------------------------------------------------------------
// attnT fp32 [z][kk][q] -> attnT_w f16: w = exp2(x*log2e - L2[z,q])
// ---------------------------------------------------------------------------
__global__ __launch_bounds__(256)
void softmax_norm(const float* __restrict__ X, const float* __restrict__ L2,
                  f16* __restrict__ Y, long n4)
{
    const long idx = (long)blockIdx.x * 256 + threadIdx.x;
    if (idx >= n4) return;
    const float4 v = ((const float4*)X)[idx];
    const int c0 = (int)(idx & 511) * 4;
    const long z = idx >> 20;           // 2048*2048/4 = 2^20 float4 per z
    const float4 l = *(const float4*)(L2 + (z << 11) + c0);
    f16x4 o;
    o[0] = (f16)exp2f(v.x * LOG2E - l.x);
    o[1] = (f16)exp2f(v.y * LOG2E - l.y);
    o[2] = (f16)exp2f(v.z * LOG2E - l.z);
    o[3] = (f16)exp2f(v.w * LOG2E - l.w);
    *(f16x4*)(Y + idx * 4) = o;
}

// ---------------------------------------------------------------------------
__global__ __launch_bounds__(256)
void copy_q_kernel(const float* __restrict__ q, float* __restrict__ out, long n4)
{
    const long idx = (long)blockIdx.x * 256 + threadIdx.x;
    if (idx >= n4) return;
    const long row = idx >> 8;
    const long c4 = idx & 255;
    *(float4*)(&out[row * 2048 + c4 * 4]) =
        *(const float4*)(&q[row * 1024 + c4 * 4]);
}

// ===========================================================================
// fp32 fallback for small workspaces
// ===========================================================================
#define BM 64
#define BN 64
#define BKF 16
template<int opA, int opB>
__global__ __launch_bounds__(256)
void sgemm(const float* __restrict__ A, const float* __restrict__ B,
           float* __restrict__ C,
           int M, int N, int K, int lda, int ldb, int ldc)
{
    __shared__ float As[BKF][BM];
    __shared__ float Bs[BKF][BN];
    const int tid = threadIdx.x;
    const int tx = tid & 15, ty = tid >> 4;
    const int bm = blockIdx.y * BM, bn = blockIdx.x * BN;
    float acc[4][4] = {};
    for (int k0 = 0; k0 < K; k0 += BKF) {
        if (opA == 0) {
            const int row = tid >> 2, kq = (tid & 3) * 4;
            const float4 v = *(const float4*)(A + (long)(bm + row) * lda + (k0 + kq));
            As[kq + 0][row] = v.x; As[kq + 1][row] = v.y;
            As[kq + 2][row] = v.z; As[kq + 3][row] = v.w;
        } else {
            const int kk = tid >> 4, mq = (tid & 15) * 4;
            *(float4*)(&As[kk][mq]) =
                *(const float4*)(A + (long)(k0 + kk) * lda + (bm + mq));
        }
        if (opB == 0) {
            const int kk = tid >> 4, nq = (tid & 15) * 4;
            *(float4*)(&Bs[kk][nq]) =
                *(const float4*)(B + (long)(k0 + kk) * ldb + (bn + nq));
        } else {
            const int row = tid >> 2, kq = (tid & 3) * 4;
            const float4 v = *(const float4*)(B + (long)(bn + row) * ldb + (k0 + kq));
            Bs[kq + 0][row] = v.x; Bs[kq + 1][row] = v.y;
            Bs[kq + 2][row] = v.z; Bs[kq + 3][row] = v.w;
        }
        __syncthreads();
        #pragma unroll
        for (int kk = 0; kk < BKF; ++kk) {
            const float4 a = *(const float4*)(&As[kk][ty * 4]);
            const float4 b = *(const float4*)(&Bs[kk][tx * 4]);
            const float av[4] = {a.x, a.y, a.z, a.w};
            const float bv[4] = {b.x, b.y, b.z, b.w};
            #pragma unroll
            for (int i = 0; i < 4; ++i)
                #pragma unroll
                for (int j = 0; j < 4; ++j)
                    acc[i][j] += av[i] * bv[j];
        }
        __syncthreads();
    }
    #pragma unroll
    for (int i = 0; i < 4; ++i) {
        const float4 v = make_float4(acc[i][0], acc[i][1], acc[i][2], acc[i][3]);
        *(float4*)(&C[(long)(bm + ty * 4 + i) * ldc + (bn + tx * 4)]) = v;
    }
}

__device__ __forceinline__ float wave_reduce_max(float v) {
    #pragma unroll
    for (int off = 1; off < 64; off <<= 1)
        v = fmaxf(v, __shfl_xor(v, off, 64));
    return v;
}
__device__ __forceinline__ float wave_reduce_sum(float v) {
    #pragma unroll
    for (int off = 1; off < 64; off <<= 1)
        v += __shfl_xor(v, off, 64);
    return v;
}

__global__ __launch_bounds__(256)
void softmax_rows2048(float* __restrict__ X)
{
    float* x = X + (long)blockIdx.x * 2048;
    const int tid = threadIdx.x;
    float4 v0 = *(const float4*)(&x[tid * 4]);
    float4 v1 = *(const float4*)(&x[1024 + tid * 4]);
    float m = fmaxf(fmaxf(fmaxf(v0.x, v0.y), fmaxf(v0.z, v0.w)),
                    fmaxf(fmaxf(v1.x, v1.y), fmaxf(v1.z, v1.w)));
    m = wave_reduce_max(m);
    __shared__ float sm[4];
    __shared__ float ss[4];
    const int wid = tid >> 6;
    if ((tid & 63) == 0) sm[wid] = m;
    __syncthreads();
    m = fmaxf(fmaxf(sm[0], sm[1]), fmaxf(sm[2], sm[3]));
    v0.x = expf(v0.x - m); v0.y = expf(v0.y - m);
    v0.z = expf(v0.z - m); v0.w = expf(v0.w - m);
    v1.x = expf(v1.x - m); v1.y = expf(v1.y - m);
    v1.w = expf(v1.w - m); v1.z = expf(v1.z - m);
    float s = (v0.x + v0.y + v0.z + v0.w) + (v1.x + v1.y + v1.z + v1.w);
    s = wave_reduce_sum(s);
    if ((tid & 63) == 0) ss[wid] = s;
    __syncthreads();
    s = ss[0] + ss[1] + ss[2] + ss[3];
    const float inv = 1.0f / s;
    v0.x *= inv; v0.y *= inv; v0.z *= inv; v0.w *= inv;
    v1.x *= inv; v1.y *= inv; v1.z *= inv; v1.w *= inv;
    *(float4*)(&x[tid * 4]) = v0;
    *(float4*)(&x[1024 + tid * 4]) = v1;
}

static void fallback_fp32(const float* q, const float* k, const float* Wq,
                          const float* Wk, const float* Wv, float* out,
                          void* d_ws, hipStream_t stream)
{
    const int S = 2048, D = 1024, O = 1024, B = 8;
    float* qp = (float*)d_ws;
    float* kp = qp + (size_t)S * O;
    float* vp = kp + (size_t)S * O;
    float* attn = vp + (size_t)S * O;
    const long n4 = (long)B * S * D / 4;
    copy_q_kernel<<<dim3((n4 + 255) / 256), 256, 0, stream>>>(q, out, n4);
    const dim3 blk(256);
    const dim3 gproj(O / BN, S / BM), gattn(S / BN, S / BM), gctx(O / BN, S / BM);
    for (int b = 0; b < B; ++b) {
        const float* qb = q + (size_t)b * S * D;
        const float* kb = k + (size_t)b * S * D;
        float* outc = out + (size_t)b * S * 2048 + D;
        sgemm<0, 0><<<gproj, blk, 0, stream>>>(qb, Wq, qp, S, O, D, D, O, O);
        sgemm<0, 0><<<gproj, blk, 0, stream>>>(kb, Wk, kp, S, O, D, D, O, O);
        sgemm<0, 0><<<gproj, blk, 0, stream>>>(kb, Wv, vp, S, O, D, D, O, O);
        sgemm<0, 1><<<gattn, blk, 0, stream>>>(qp, kp, attn, S, S, O, O, O, S);
        softmax_rows2048<<<dim3(S), blk, 0, stream>>>(attn);
        sgemm<1, 0><<<gctx, blk, 0, stream>>>(attn, vp, outc, S, O, S, S, O, 2048);
    }
}

// ===========================================================================
extern "C" void kernel_launch(void* const* d_in, const int* in_sizes, int n_in,
                              void* d_out, int out_size, void* d_ws, size_t ws_size,
                              hipStream_t stream)
{
    const float* q  = (const float*)d_in[0];
    const float* k  = (const float*)d_in[1];
    const float* Wq = (const float*)d_in[2];
    const float* Wk = (const float*)d_in[3];
    const float* Wv = (const float*)d_in[4];
    float* out = (float*)d_out;

    const int B = 8, S = 2048;

    auto need = [](int g) -> size_t {
        const size_t wpk  = 2 * (size_t)1024 * 2048 * 2 + (size_t)1024 * 1024 * 2;
        const size_t pk   = (size_t)g * 2048 * 2048 * 2;   // x4 (qpack,kpack,qp,kp)
        const size_t vpT  = (size_t)1024 * g * 2048 * 2;
        const size_t attn = (size_t)g * 2048 * 2048 * 4;
        const size_t aw   = (size_t)g * 2048 * 2048 * 2;
        const size_t pp   = 2 * (size_t)g * 8 * 2048 * 4 + (size_t)g * 2048 * 4;
        return wpk + 4 * pk + vpT + attn + aw + pp + 32 * 256;
    };
    int g = 0;
    for (int cand : {8, 4, 2, 1})
        if (need(cand) <= ws_size) { g = cand; break; }
    if (g == 0) { fallback_fp32(q, k, Wq, Wk, Wv, out, d_ws, stream); return; }

    char* p = (char*)d_ws;
    auto carve = [&](size_t bytes) {
        char* r = p;
        p += (bytes + 255) & ~(size_t)255;
        return r;
    };
    f16* Wtq = (f16*)carve((size_t)1024 * 2048 * 2);
    f16* Wtk = (f16*)carve((size_t)1024 * 2048 * 2);
    f16* Wtv = (f16*)carve((size_t)1024 * 1024 * 2);
    const size_t pkB = (size_t)g * 2048 * 2048 * 2;
    f16* qpack   = (f16*)carve(pkB);
    f16* kpack   = (f16*)carve(pkB);
    f16* qp_pack = (f16*)carve(pkB);
    f16* kp_pack = (f16*)carve(pkB);
    f16* vpT     = (f16*)carve((size_t)1024 * g * 2048 * 2);
    float* attnT = (float*)carve((size_t)g * 2048 * 2048 * 4);
    f16* attn_w  = (f16*)carve((size_t)g * 2048 * 2048 * 2);
    float* pmb   = (float*)carve((size_t)g * 8 * 2048 * 4);
    float* psb   = (float*)carve((size_t)g * 8 * 2048 * 4);
    float* L2    = (float*)carve((size_t)g * 2048 * 4);

    pack_W_T<1><<<dim3(16, 16), 256, 0, stream>>>(Wq, Wtq);
    pack_W_T<1><<<dim3(16, 16), 256, 0, stream>>>(Wk, Wtk);
    pack_W_T<0><<<dim3(16, 16), 256, 0, stream>>>(Wv, Wtv);

    {
        const long n4 = (long)B * S * 1024 / 4;
        copy_q_kernel<<<dim3((n4 + 255) / 256), 256, 0, stream>>>(q, out, n4);
    }

    const int Mg = g * 2048;
    const dim3 blk(256);
    const dim3 blk512(512);
    const long zSS = (long)2048 * 2048;

    for (int gi = 0; gi < B / g; ++gi) {
        const float* qg = q + (size_t)gi * Mg * 1024;
        const float* kg = k + (size_t)gi * Mg * 1024;

        const long nquads = (long)Mg * 256;
        pack_rows_HL<<<dim3((nquads + 255) / 256), blk, 0, stream>>>(qg, qpack, nquads);
        pack_rows_HL<<<dim3((nquads + 255) / 256), blk, 0, stream>>>(kg, kpack, nquads);

        // projections: A=[hi,lo] (K'=2048) x B=[hi,hi]
        const dim3 g1((1024 / 256) * (Mg / 256), 1, 1);
        gemm256<CM_PACK_HH><<<g1, blk512, 0, stream>>>(
            qpack, Wtq, qp_pack, Mg, 1024, 2048, 2048, 2048, 0, 0, 0, 0,
            nullptr, nullptr);
        gemm256<CM_PACK_HL><<<g1, blk512, 0, stream>>>(
            kpack, Wtk, kp_pack, Mg, 1024, 2048, 2048, 2048, 0, 0, 0, 0,
            nullptr, nullptr);
        // V projection: plain fp16, K=1024 (hi half of kpack), C^T out
        gemm256<CM_F16T><<<g1, blk512, 0, stream>>>(
            kpack, Wtv, vpT, Mg, 1024, 1024, 2048, 1024, Mg, 0, 0, 0,
            nullptr, nullptr);

        // attnT = kp @ qp^T per z, fp32 out + fused column partials
        const dim3 g2((2048 / 256) * (2048 / 256), 1, g);
        gemm256<CM_ATTN><<<g2, blk512, 0, stream>>>(
            kp_pack, qp_pack, attnT, 2048, 2048, 2048, 2048, 2048, 2048,
            zSS, zSS, zSS, pmb, psb);

        // merge partials -> L2; normalize -> fp16 attn_w (transposed layout)
        const int nq = g * 2048;
        softmax_merge<<<dim3((nq + 255) / 256), blk, 0, stream>>>(pmb, psb, L2, nq);
        const long n4 = (long)g * 2048 * 512;
        softmax_norm<<<dim3((n4 + 255) / 256), blk, 0, stream>>>(attnT, L2, attn_w, n4);

        // context = attn_w @ vpT^T -> out cols 1024..2047
        float* outg = out + (size_t)gi * Mg * 2048 + 1024;
        const dim3 g3((1024 / 256) * (2048 / 256), 1, g);
        gemm256<CM_F32><<<g3, blk512, 0, stream>>>(
            attn_w, vpT, outg, 2048, 1024, 2048, 2048, Mg, 2048,
            zSS, 2048, zSS, nullptr, nullptr);
    }
}

// Round 5
// 540.134 us; speedup vs baseline: 6.8336x; 1.0219x over previous
//
#include <hip/hip_runtime.h>
#include <hip/hip_bf16.h>

// B=8, S=2048, D=1024, O=1024
// qp=q@Wq, kp=k@Wk, vp=k@Wv ; attn=qp@kp^T (no scale); w=softmax(attn,-1)
// context = attn_w^T @ vp ; out = concat([q, context], -1)  fp32 [B,S,2048]
//
// fp16 2-term split: x = hi + lo. One-sided [hiA,loA]@[hiB,hiB] over K'=2K.
// attnT = kp @ qp^T computed transposed; epilogue writes f16 e=exp(l-M_blk)
// + per-128-row-block partials; merge builds scale table; in-place rescale;
// PV consumes rescaled weights directly.
//
// GEMM inner loop: 256x256 tile, BK=64, 8 waves (2Mx4N), 32x32x16 f16 MFMA
// (8/phase), 4 phases/K-tile, counted vmcnt(4), setprio, XCD swizzle.

typedef __attribute__((ext_vector_type(4))) float f32x4;
typedef __attribute__((ext_vector_type(16))) float f32x16;
typedef _Float16 f16;
typedef __attribute__((ext_vector_type(8))) _Float16 f16x8;
typedef __attribute__((ext_vector_type(4))) _Float16 f16x4;

#define LOG2E 1.4426950408889634f

#define CM_F32     0
#define CM_PACK_HH 1
#define CM_PACK_HL 2
#define CM_F16T    3
#define CM_ATTN    4

// Stage one 16 KiB unit (WHICH: 0=A,1=B; KS: k-half) of K-tile KT into buffer
// at byte offset BO. LDS dst linear in tid; XOR swizzle applied by
// pre-swizzling the GLOBAL source k-chunk (both-sides-or-neither).
#define STAGE(WHICH, KS, KT, BO) do { \
    const char* _gb = (WHICH) ? Bb : Ab; \
    const int _ld = (WHICH) ? ldb : lda; \
    const long _r = (WHICH) ? (long)(bn + srow0) : (long)(bm + srow0); \
    const int _k0 = (KT) * 64 + (KS) * 32 + sh8; \
    char* _dst = (char*)smem + (BO) + (WHICH) * 32768 + (KS) * 16384 + wave * 1024; \
    const char* _g0 = _gb + ((_r * _ld + _k0) << 1); \
    const char* _g1 = _gb + (((_r + 128) * _ld + _k0) << 1); \
    __builtin_amdgcn_global_load_lds((const __attribute__((address_space(1))) void*)_g0, \
        (__attribute__((address_space(3))) void*)_dst, 16, 0, 0); \
    __builtin_amdgcn_global_load_lds((const __attribute__((address_space(1))) void*)_g1, \
        (__attribute__((address_space(3))) void*)(_dst + 8192), 16, 0, 0); \
} while (0)

// One phase: k-step S (0/1) of unit KS. 4 A-frags + 2 B-frags (6 ds_read_b128)
// -> stage issue -> barrier -> (compiler lgkmcnt) -> 8 MFMA 32x32x16.
#define GPHASE32(KS, S, STAGE_CODE, VM) do { \
    f16x8 af[4], bb[2]; \
    _Pragma("unroll") \
    for (int mt = 0; mt < 4; ++mt) \
        af[mt] = *(const f16x8*)(smem + ((bufo + (KS) * 16384 + abase[mt]) ^ ((S) << 5))); \
    _Pragma("unroll") \
    for (int nt = 0; nt < 2; ++nt) \
        bb[nt] = *(const f16x8*)(smem + ((bufo + (KS) * 16384 + bbase[nt]) ^ ((S) << 5))); \
    STAGE_CODE; \
    __builtin_amdgcn_sched_barrier(0); \
    __builtin_amdgcn_s_barrier(); \
    __builtin_amdgcn_sched_barrier(0); \
    __builtin_amdgcn_s_setprio(1); \
    _Pragma("unroll") \
    for (int mt = 0; mt < 4; ++mt) \
        _Pragma("unroll") \
        for (int nt = 0; nt < 2; ++nt) \
            acc[mt][nt] = __builtin_amdgcn_mfma_f32_32x32x16_f16( \
                af[mt], bb[nt], acc[mt][nt], 0, 0, 0); \
    __builtin_amdgcn_s_setprio(0); \
    VM; \
    __builtin_amdgcn_sched_barrier(0); \
    __builtin_amdgcn_s_barrier(); \
    __builtin_amdgcn_sched_barrier(0); \
} while (0)

template<int CMODE>
__global__ __launch_bounds__(512, 2)
void gemm256(const f16* __restrict__ A, const f16* __restrict__ B,
             void* __restrict__ Cv,
             int M, int N, int K, int lda, int ldb, int ldc,
             long az, long bz, long cz,
             float* __restrict__ pm, float* __restrict__ ps)
{
    __shared__ __align__(16) char smem[131072];

    const int z = blockIdx.z;
    const char* Ab = (const char*)(A + z * az);
    const char* Bb = (const char*)(B + z * bz);

    // XCD-aware swizzle (all launches have nwg % 8 == 0)
    const int nbx = N >> 8;
    int wg = blockIdx.x;
    const int nwg = gridDim.x;
    if ((nwg & 7) == 0) wg = (wg & 7) * (nwg >> 3) + (wg >> 3);
    const int bm = (wg / nbx) << 8;
    const int bn = (wg % nbx) << 8;

    const int tid = threadIdx.x;
    const int wave = tid >> 6;
    const int lane = tid & 63;
    const int l31 = lane & 31;
    const int h5 = lane >> 5;
    const int wm = wave >> 2;      // 0..1 -> rows wm*128..+128
    const int wn = wave & 3;       // 0..3 -> cols wn*64..+64

    // swizzled slot: slot = (2*S ^ h5 ^ f) with f = (row ^ row>>2)&3
    const int f3 = (l31 ^ (l31 >> 2)) & 3;
    const int sl = ((h5 ^ f3) << 4);
    int abase[4], bbase[2];
    #pragma unroll
    for (int mt = 0; mt < 4; ++mt)
        abase[mt] = (wm * 128 + mt * 32 + l31) * 64 + sl;
    #pragma unroll
    for (int nt = 0; nt < 2; ++nt)
        bbase[nt] = 32768 + (wn * 64 + nt * 32 + l31) * 64 + sl;

    // staging per-thread constants
    const int srow0 = tid >> 2;
    const int sh8 = ((tid ^ (tid >> 2) ^ (tid >> 4)) & 3) * 8;

    f32x16 acc[4][2];
    #pragma unroll
    for (int mt = 0; mt < 4; ++mt)
        #pragma unroll
        for (int nt = 0; nt < 2; ++nt)
            acc[mt][nt] = (f32x16)(0.f);

    const int nt_k = K >> 6;

    {
        const int t1p = (nt_k > 1) ? 1 : 0;
        STAGE(0, 0, 0, 0);
        STAGE(1, 0, 0, 0);
        STAGE(0, 1, 0, 0);
        STAGE(1, 1, 0, 0);
        STAGE(0, 0, t1p, 65536);
        STAGE(1, 0, t1p, 65536);
        asm volatile("s_waitcnt vmcnt(4)" ::: "memory");
        __builtin_amdgcn_sched_barrier(0);
        __builtin_amdgcn_s_barrier();
        __builtin_amdgcn_sched_barrier(0);
    }

    for (int t = 0; t < nt_k; ++t) {
        const int bufo = (t & 1) << 16;
        const int nbo = bufo ^ 65536;
        const int t1 = (t + 1 < nt_k) ? t + 1 : nt_k - 1;
        const int t2 = (t + 2 < nt_k) ? t + 2 : nt_k - 1;
        GPHASE32(0, 0, STAGE(0, 1, t1, nbo), );
        GPHASE32(0, 1, STAGE(1, 1, t1, nbo), );
        GPHASE32(1, 0, STAGE(0, 0, t2, bufo), );
        GPHASE32(1, 1, STAGE(1, 0, t2, bufo),
                 asm volatile("s_waitcnt vmcnt(4)" ::: "memory"));
    }
    // drain pending LDS-DMA before the workgroup can exit
    asm volatile("s_waitcnt vmcnt(0)" ::: "memory");

    // ---- epilogue: 32x32 D mapping col=lane&31, row=(reg&3)+4*(lane>>5)+8*(reg>>2)
    if (CMODE == CM_ATTN) {
        f16* E = (f16*)Cv + z * cz;
        #pragma unroll
        for (int nt = 0; nt < 2; ++nt) {
            float Mx = -3.4e38f;
            #pragma unroll
            for (int mt = 0; mt < 4; ++mt)
                #pragma unroll
                for (int r = 0; r < 16; ++r)
                    Mx = fmaxf(Mx, acc[mt][nt][r]);
            Mx = fmaxf(Mx, __shfl_xor(Mx, 32, 64));
            float Sm = 0.f;
            #pragma unroll
            for (int mt = 0; mt < 4; ++mt)
                #pragma unroll
                for (int r = 0; r < 16; ++r) {
                    const float e = exp2f((acc[mt][nt][r] - Mx) * LOG2E);
                    acc[mt][nt][r] = e;
                    Sm += e;
                }
            Sm += __shfl_xor(Sm, 32, 64);
            const int col = bn + wn * 64 + nt * 32 + l31;
            #pragma unroll
            for (int mt = 0; mt < 4; ++mt) {
                const int row0 = bm + wm * 128 + mt * 32 + h5 * 4;
                #pragma unroll
                for (int rq = 0; rq < 4; ++rq)
                    #pragma unroll
                    for (int rr = 0; rr < 4; ++rr)
                        E[(long)(row0 + rq * 8 + rr) * ldc + col] =
                            (f16)acc[mt][nt][rq * 4 + rr];
            }
            if (lane < 32) {
                const long pidx = ((long)z * 16 + (bm >> 7) + wm) * N + col;
                pm[pidx] = Mx * LOG2E;   // log2 domain
                ps[pidx] = Sm;
            }
        }
        return;
    }

    #pragma unroll
    for (int mt = 0; mt < 4; ++mt) {
        #pragma unroll
        for (int nt = 0; nt < 2; ++nt) {
            const int row0 = bm + wm * 128 + mt * 32 + h5 * 4;
            const int col = bn + wn * 64 + nt * 32 + l31;
            if (CMODE == CM_F32) {
                float* C = (float*)Cv + z * cz;
                #pragma unroll
                for (int rq = 0; rq < 4; ++rq)
                    #pragma unroll
                    for (int rr = 0; rr < 4; ++rr)
                        C[(long)(row0 + rq * 8 + rr) * ldc + col] =
                            acc[mt][nt][rq * 4 + rr];
            } else if (CMODE == CM_PACK_HH || CMODE == CM_PACK_HL) {
                f16* C = (f16*)Cv + z * cz;
                #pragma unroll
                for (int rq = 0; rq < 4; ++rq)
                    #pragma unroll
                    for (int rr = 0; rr < 4; ++rr) {
                        const float v = acc[mt][nt][rq * 4 + rr];
                        const f16 h = (f16)v;
                        const long base = (long)(row0 + rq * 8 + rr) * (2LL * N) + col;
                        C[base] = h;
                        C[base + N] = (CMODE == CM_PACK_HH) ? h : (f16)(v - (float)h);
                    }
            } else { // CM_F16T: C^T[col][rows]
                f16* C = (f16*)Cv + z * cz;
                #pragma unroll
                for (int rq = 0; rq < 4; ++rq) {
                    f16x4 v;
                    #pragma unroll
                    for (int rr = 0; rr < 4; ++rr) v[rr] = (f16)acc[mt][nt][rq * 4 + rr];
                    *(f16x4*)(C + (long)col * ldc + row0 + rq * 8) = v;
                }
            }
        }
    }
}

// ---------------------------------------------------------------------------
// fp32 rows [R,1024] -> f16 [R,2048] as [hi | lo]
// ---------------------------------------------------------------------------
__global__ __launch_bounds__(256)
void pack_rows_HL(const float* __restrict__ in, f16* __restrict__ out, long nquads)
{
    const long i = (long)blockIdx.x * 256 + threadIdx.x;
    if (i >= nquads) return;
    const long row = i >> 8;
    const int c = (int)(i & 255) * 4;
    const float4 v = *(const float4*)(in + row * 1024 + c);
    const float vv[4] = {v.x, v.y, v.z, v.w};
    f16x4 h, l;
    #pragma unroll
    for (int j = 0; j < 4; ++j) {
        h[j] = (f16)vv[j];
        l[j] = (f16)(vv[j] - (float)h[j]);
    }
    f16* o = out + row * 2048 + c;
    *(f16x4*)o = h;
    *(f16x4*)(o + 1024) = l;
}

// ---------------------------------------------------------------------------
// W [1024 d][1024 o] fp32 -> Wt [o][2048]=[hi|hi] (DUP2=1) or [o][1024] (DUP2=0)
// ---------------------------------------------------------------------------
template<int DUP2>
__global__ __launch_bounds__(256)
void pack_W_T(const float* __restrict__ W, f16* __restrict__ Wt)
{
    __shared__ float tile[64][65];
    const int d0 = blockIdx.y * 64, o0 = blockIdx.x * 64;
    const int t = threadIdx.x;
    const int rr = t >> 4, c4 = (t & 15) * 4;
    #pragma unroll
    for (int it = 0; it < 4; ++it) {
        const int r = rr + it * 16;
        const float4 v = *(const float4*)(W + (long)(d0 + r) * 1024 + o0 + c4);
        tile[r][c4] = v.x; tile[r][c4 + 1] = v.y;
        tile[r][c4 + 2] = v.z; tile[r][c4 + 3] = v.w;
    }
    __syncthreads();
    #pragma unroll
    for (int it = 0; it < 4; ++it) {
        const int orow = rr + it * 16;
        f16x4 h;
        #pragma unroll
        for (int j = 0; j < 4; ++j) h[j] = (f16)tile[c4 + j][orow];
        f16* o = Wt + (long)(o0 + orow) * (DUP2 ? 2048 : 1024) + d0 + c4;
        *(f16x4*)o = h;
        if (DUP2) *(f16x4*)(o + 1024) = h;
    }
}

// ---------------------------------------------------------------------------
// merge 16 per-block partials -> scale[z][16][2048] = exp2(pm - L)
// ---------------------------------------------------------------------------
__global__ __launch_bounds__(256)
void softmax_merge16(const float* __restrict__ pm, const float* __restrict__ ps,
                     float* __restrict__ scale, int nq)
{
    const int idx = blockIdx.x * 256 + threadIdx.x;
    if (idx >= nq) return;
    const int z = idx >> 11, q = idx & 2047;
    const float* pmz = pm + ((long)z * 16) * 2048 + q;
    const float* psz = ps + ((long)z * 16) * 2048 + q;
    float mx = -3.4e38f;
    #pragma unroll
    for (int j = 0; j < 16; ++j) mx = fmaxf(mx, pmz[j * 2048]);
    float s = 0.f;
    #pragma unroll
    for (int j = 0; j < 16; ++j)
        s += psz[j * 2048] * exp2f(pmz[j * 2048] - mx);
    const float L = mx + log2f(s);
    float* sc = scale + ((long)z * 16) * 2048 + q;
    #pragma unroll
    for (int j = 0; j < 16; ++j)
        sc[j * 2048] = exp2f(pmz[j * 2048] - L);
}

// ---------------------------------------------------------------------------
// in-place rescale: e[z][kk][q] *= scale[z][kk>>7][q]   (8 f16 per thread)
// ---------------------------------------------------------------------------
__global__ __launch_bounds__(256)
void rescale_e(f16* __restrict__ e, const float* __restrict__ scale, long n8)
{
    const long idx = (long)blockIdx.x * 256 + threadIdx.x;
    if (idx >= n8) return;
    const long z = idx >> 19;                 // 2^19 groups of 8 per z
    const int within = (int)(idx & ((1 << 19) - 1));
    const int kk = within >> 8;
    const int q8 = (within & 255) * 8;
    const float* sc = scale + ((long)z * 16 + (kk >> 7)) * 2048 + q8;
    const float4 s0 = *(const float4*)sc;
    const float4 s1 = *(const float4*)(sc + 4);
    f16x8 v = *(f16x8*)(e + idx * 8);
    v[0] = (f16)((float)v[0] * s0.x); v[1] = (f16)((float)v[1] * s0.y);
    v[2] = (f16)((float)v[2] * s0.z); v[3] = (f16)((float)v[3] * s0.w);
    v[4] = (f16)((float)v[4] * s1.x); v[5] = (f16)((float)v[5] * s1.y);
    v[6] = (f16)((float)v[6] * s1.z); v[7] = (f16)((float)v[7] * s1.w);
    *(f16x8*)(e + idx * 8) = v;
}

// ---------------------------------------------------------------------------
__global__ __launch_bounds__(256)
void copy_q_kernel(const float* __restrict__ q, float* __restrict__ out, long n4)
{
    const long idx = (long)blockIdx.x * 256 + threadIdx.x;
    if (idx >= n4) return;
    const long row = idx >> 8;
    const long c4 = idx & 255;
    *(float4*)(&out[row * 2048 + c4 * 4]) =
        *(const float4*)(&q[row * 1024 + c4 * 4]);
}

// ===========================================================================
// fp32 fallback for small workspaces
// ===========================================================================
#define BM 64
#define BN 64
#define BKF 16
template<int opA, int opB>
__global__ __launch_bounds__(256)
void sgemm(const float* __restrict__ A, const float* __restrict__ B,
           float* __restrict__ C,
           int M, int N, int K, int lda, int ldb, int ldc)
{
    __shared__ float As[BKF][BM];
    __shared__ float Bs[BKF][BN];
    const int tid = threadIdx.x;
    const int tx = tid & 15, ty = tid >> 4;
    const int bm = blockIdx.y * BM, bn = blockIdx.x * BN;
    float acc[4][4] = {};
    for (int k0 = 0; k0 < K; k0 += BKF) {
        if (opA == 0) {
            const int row = tid >> 2, kq = (tid & 3) * 4;
            const float4 v = *(const float4*)(A + (long)(bm + row) * lda + (k0 + kq));
            As[kq + 0][row] = v.x; As[kq + 1][row] = v.y;
            As[kq + 2][row] = v.z; As[kq + 3][row] = v.w;
        } else {
            const int kk = tid >> 4, mq = (tid & 15) * 4;
            *(float4*)(&As[kk][mq]) =
                *(const float4*)(A + (long)(k0 + kk) * lda + (bm + mq));
        }
        if (opB == 0) {
            const int kk = tid >> 4, nq = (tid & 15) * 4;
            *(float4*)(&Bs[kk][nq]) =
                *(const float4*)(B + (long)(k0 + kk) * ldb + (bn + nq));
        } else {
            const int row = tid >> 2, kq = (tid & 3) * 4;
            const float4 v = *(const float4*)(B + (long)(bn + row) * ldb + (k0 + kq));
            Bs[kq + 0][row] = v.x; Bs[kq + 1][row] = v.y;
            Bs[kq + 2][row] = v.z; Bs[kq + 3][row] = v.w;
        }
        __syncthreads();
        #pragma unroll
        for (int kk = 0; kk < BKF; ++kk) {
            const float4 a = *(const float4*)(&As[kk][ty * 4]);
            const float4 b = *(const float4*)(&Bs[kk][tx * 4]);
            const float av[4] = {a.x, a.y, a.z, a.w};
            const float bv[4] = {b.x, b.y, b.z, b.w};
            #pragma unroll
            for (int i = 0; i < 4; ++i)
                #pragma unroll
                for (int j = 0; j < 4; ++j)
                    acc[i][j] += av[i] * bv[j];
        }
        __syncthreads();
    }
    #pragma unroll
    for (int i = 0; i < 4; ++i) {
        const float4 v = make_float4(acc[i][0], acc[i][1], acc[i][2], acc[i][3]);
        *(float4*)(&C[(long)(bm + ty * 4 + i) * ldc + (bn + tx * 4)]) = v;
    }
}

__device__ __forceinline__ float wave_reduce_max(float v) {
    #pragma unroll
    for (int off = 1; off < 64; off <<= 1)
        v = fmaxf(v, __shfl_xor(v, off, 64));
    return v;
}
__device__ __forceinline__ float wave_reduce_sum(float v) {
    #pragma unroll
    for (int off = 1; off < 64; off <<= 1)
        v += __shfl_xor(v, off, 64);
    return v;
}

__global__ __launch_bounds__(256)
void softmax_rows2048(float* __restrict__ X)
{
    float* x = X + (long)blockIdx.x * 2048;
    const int tid = threadIdx.x;
    float4 v0 = *(const float4*)(&x[tid * 4]);
    float4 v1 = *(const float4*)(&x[1024 + tid * 4]);
    float m = fmaxf(fmaxf(fmaxf(v0.x, v0.y), fmaxf(v0.z, v0.w)),
                    fmaxf(fmaxf(v1.x, v1.y), fmaxf(v1.z, v1.w)));
    m = wave_reduce_max(m);
    __shared__ float sm[4];
    __shared__ float ss[4];
    const int wid = tid >> 6;
    if ((tid & 63) == 0) sm[wid] = m;
    __syncthreads();
    m = fmaxf(fmaxf(sm[0], sm[1]), fmaxf(sm[2], sm[3]));
    v0.x = expf(v0.x - m); v0.y = expf(v0.y - m);
    v0.z = expf(v0.z - m); v0.w = expf(v0.w - m);
    v1.x = expf(v1.x - m); v1.y = expf(v1.y - m);
    v1.z = expf(v1.z - m); v1.w = expf(v1.w - m);
    float s = (v0.x + v0.y + v0.z + v0.w) + (v1.x + v1.y + v1.z + v1.w);
    s = wave_reduce_sum(s);
    if ((tid & 63) == 0) ss[wid] = s;
    __syncthreads();
    s = ss[0] + ss[1] + ss[2] + ss[3];
    const float inv = 1.0f / s;
    v0.x *= inv; v0.y *= inv; v0.z *= inv; v0.w *= inv;
    v1.x *= inv; v1.y *= inv; v1.z *= inv; v1.w *= inv;
    *(float4*)(&x[tid * 4]) = v0;
    *(float4*)(&x[1024 + tid * 4]) = v1;
}

static void fallback_fp32(const float* q, const float* k, const float* Wq,
                          const float* Wk, const float* Wv, float* out,
                          void* d_ws, hipStream_t stream)
{
    const int S = 2048, D = 1024, O = 1024, B = 8;
    float* qp = (float*)d_ws;
    float* kp = qp + (size_t)S * O;
    float* vp = kp + (size_t)S * O;
    float* attn = vp + (size_t)S * O;
    const long n4 = (long)B * S * D / 4;
    copy_q_kernel<<<dim3((n4 + 255) / 256), 256, 0, stream>>>(q, out, n4);
    const dim3 blk(256);
    const dim3 gproj(O / BN, S / BM), gattn(S / BN, S / BM), gctx(O / BN, S / BM);
    for (int b = 0; b < B; ++b) {
        const float* qb = q + (size_t)b * S * D;
        const float* kb = k + (size_t)b * S * D;
        float* outc = out + (size_t)b * S * 2048 + D;
        sgemm<0, 0><<<gproj, blk, 0, stream>>>(qb, Wq, qp, S, O, D, D, O, O);
        sgemm<0, 0><<<gproj, blk, 0, stream>>>(kb, Wk, kp, S, O, D, D, O, O);
        sgemm<0, 0><<<gproj, blk, 0, stream>>>(kb, Wv, vp, S, O, D, D, O, O);
        sgemm<0, 1><<<gattn, blk, 0, stream>>>(qp, kp, attn, S, S, O, O, O, S);
        softmax_rows2048<<<dim3(S), blk, 0, stream>>>(attn);
        sgemm<1, 0><<<gctx, blk, 0, stream>>>(attn, vp, outc, S, O, S, S, O, 2048);
    }
}

// ===========================================================================
extern "C" void kernel_launch(void* const* d_in, const int* in_sizes, int n_in,
                              void* d_out, int out_size, void* d_ws, size_t ws_size,
                              hipStream_t stream)
{
    const float* q  = (const float*)d_in[0];
    const float* k  = (const float*)d_in[1];
    const float* Wq = (const float*)d_in[2];
    const float* Wk = (const float*)d_in[3];
    const float* Wv = (const float*)d_in[4];
    float* out = (float*)d_out;

    const int B = 8, S = 2048;

    auto need = [](int g) -> size_t {
        const size_t wpk = 2 * (size_t)1024 * 2048 * 2 + (size_t)1024 * 1024 * 2;
        const size_t pk  = (size_t)g * 2048 * 2048 * 2;   // x4
        const size_t vpT = (size_t)1024 * g * 2048 * 2;
        const size_t aw  = (size_t)g * 2048 * 2048 * 2;
        const size_t pp  = 3 * (size_t)g * 16 * 2048 * 4;
        return wpk + 4 * pk + vpT + aw + pp + 32 * 256;
    };
    int g = 0;
    for (int cand : {8, 4, 2, 1})
        if (need(cand) <= ws_size) { g = cand; break; }
    if (g == 0) { fallback_fp32(q, k, Wq, Wk, Wv, out, d_ws, stream); return; }

    char* p = (char*)d_ws;
    auto carve = [&](size_t bytes) {
        char* r = p;
        p += (bytes + 255) & ~(size_t)255;
        return r;
    };
    f16* Wtq = (f16*)carve((size_t)1024 * 2048 * 2);
    f16* Wtk = (f16*)carve((size_t)1024 * 2048 * 2);
    f16* Wtv = (f16*)carve((size_t)1024 * 1024 * 2);
    const size_t pkB = (size_t)g * 2048 * 2048 * 2;
    f16* qpack   = (f16*)carve(pkB);
    f16* kpack   = (f16*)carve(pkB);
    f16* qp_pack = (f16*)carve(pkB);
    f16* kp_pack = (f16*)carve(pkB);
    f16* vpT     = (f16*)carve((size_t)1024 * g * 2048 * 2);
    f16* attn_w  = (f16*)carve((size_t)g * 2048 * 2048 * 2);
    float* pmb   = (float*)carve((size_t)g * 16 * 2048 * 4);
    float* psb   = (float*)carve((size_t)g * 16 * 2048 * 4);
    float* scb   = (float*)carve((size_t)g * 16 * 2048 * 4);

    pack_W_T<1><<<dim3(16, 16), 256, 0, stream>>>(Wq, Wtq);
    pack_W_T<1><<<dim3(16, 16), 256, 0, stream>>>(Wk, Wtk);
    pack_W_T<0><<<dim3(16, 16), 256, 0, stream>>>(Wv, Wtv);

    {
        const long n4 = (long)B * S * 1024 / 4;
        copy_q_kernel<<<dim3((n4 + 255) / 256), 256, 0, stream>>>(q, out, n4);
    }

    const int Mg = g * 2048;
    const dim3 blk(256);
    const dim3 blk512(512);
    const long zSS = (long)2048 * 2048;

    for (int gi = 0; gi < B / g; ++gi) {
        const float* qg = q + (size_t)gi * Mg * 1024;
        const float* kg = k + (size_t)gi * Mg * 1024;

        const long nquads = (long)Mg * 256;
        pack_rows_HL<<<dim3((nquads + 255) / 256), blk, 0, stream>>>(qg, qpack, nquads);
        pack_rows_HL<<<dim3((nquads + 255) / 256), blk, 0, stream>>>(kg, kpack, nquads);

        // projections: A=[hi,lo] (K'=2048) x B=[hi,hi]
        const dim3 g1((1024 / 256) * (Mg / 256), 1, 1);
        gemm256<CM_PACK_HH><<<g1, blk512, 0, stream>>>(
            qpack, Wtq, qp_pack, Mg, 1024, 2048, 2048, 2048, 0, 0, 0, 0,
            nullptr, nullptr);
        gemm256<CM_PACK_HL><<<g1, blk512, 0, stream>>>(
            kpack, Wtk, kp_pack, Mg, 1024, 2048, 2048, 2048, 0, 0, 0, 0,
            nullptr, nullptr);
        // V projection: plain fp16, K=1024 (hi half of kpack), C^T out
        gemm256<CM_F16T><<<g1, blk512, 0, stream>>>(
            kpack, Wtv, vpT, Mg, 1024, 1024, 2048, 1024, Mg, 0, 0, 0,
            nullptr, nullptr);

        // attnT = kp @ qp^T per z -> f16 e + per-128-row partials
        const dim3 g2((2048 / 256) * (2048 / 256), 1, g);
        gemm256<CM_ATTN><<<g2, blk512, 0, stream>>>(
            kp_pack, qp_pack, attn_w, 2048, 2048, 2048, 2048, 2048, 2048,
            zSS, zSS, zSS, pmb, psb);

        // merge partials -> scale table; in-place rescale e -> weights
        const int nq = g * 2048;
        softmax_merge16<<<dim3((nq + 255) / 256), blk, 0, stream>>>(pmb, psb, scb, nq);
        const long n8 = (long)g * 2048 * 256;
        rescale_e<<<dim3((n8 + 255) / 256), blk, 0, stream>>>(attn_w, scb, n8);

        // context = attn_w @ vpT^T -> out cols 1024..2047
        float* outg = out + (size_t)gi * Mg * 2048 + 1024;
        const dim3 g3((1024 / 256) * (2048 / 256), 1, g);
        gemm256<CM_F32><<<g3, blk512, 0, stream>>>(
            attn_w, vpT, outg, 2048, 1024, 2048, 2048, Mg, 2048,
            zSS, 2048, zSS, nullptr, nullptr);
    }
}

// Round 6
// 453.149 us; speedup vs baseline: 8.1454x; 1.1920x over previous
//
#include <hip/hip_runtime.h>
#include <hip/hip_bf16.h>

// B=8, S=2048, D=1024, O=1024
// qp=q@Wq, kp=k@Wk, vp=k@Wv ; attn=qp@kp^T (no scale); w=softmax(attn,-1)
// context = attn_w^T @ vp ; out = concat([q, context], -1)  fp32 [B,S,2048]
//
// Precision plan: projections run plain fp16 (K=1024; input-cast error
// ~6e-3 RMS in logits, tolerable). QK^T keeps the 2-term split on the K
// side: kp stored [hi|lo], qp stored [hi|hi], K'=2048. PV plain fp16.
// attnT = kp @ qp^T computed transposed; epilogue writes f16 e=exp(l-M_blk)
// + per-128-row partials; merge builds scale table; in-place rescale; PV.
//
// GEMM: 256x256 tile, BK=64, 8 waves (2Mx4N), 32x32x16 f16 MFMA (8/phase),
// 4 phases/K-tile, counted vmcnt(4), setprio, XCD swizzle, conflict-free LDS.

typedef __attribute__((ext_vector_type(4))) float f32x4;
typedef __attribute__((ext_vector_type(16))) float f32x16;
typedef _Float16 f16;
typedef __attribute__((ext_vector_type(8))) _Float16 f16x8;
typedef __attribute__((ext_vector_type(4))) _Float16 f16x4;

#define LOG2E 1.4426950408889634f

#define CM_F32     0
#define CM_PACK_HH 1
#define CM_PACK_HL 2
#define CM_F16T    3
#define CM_ATTN    4

// Stage one 16 KiB unit (WHICH: 0=A,1=B; KS: k-half) of K-tile KT into buffer
// at byte offset BO. LDS dst linear in tid; XOR swizzle applied by
// pre-swizzling the GLOBAL source k-chunk (both-sides-or-neither).
#define STAGE(WHICH, KS, KT, BO) do { \
    const char* _gb = (WHICH) ? Bb : Ab; \
    const int _ld = (WHICH) ? ldb : lda; \
    const long _r = (WHICH) ? (long)(bn + srow0) : (long)(bm + srow0); \
    const int _k0 = (KT) * 64 + (KS) * 32 + sh8; \
    char* _dst = (char*)smem + (BO) + (WHICH) * 32768 + (KS) * 16384 + wave * 1024; \
    const char* _g0 = _gb + ((_r * _ld + _k0) << 1); \
    const char* _g1 = _gb + (((_r + 128) * _ld + _k0) << 1); \
    __builtin_amdgcn_global_load_lds((const __attribute__((address_space(1))) void*)_g0, \
        (__attribute__((address_space(3))) void*)_dst, 16, 0, 0); \
    __builtin_amdgcn_global_load_lds((const __attribute__((address_space(1))) void*)_g1, \
        (__attribute__((address_space(3))) void*)(_dst + 8192), 16, 0, 0); \
} while (0)

// One phase: k-step S (0/1) of unit KS. 4 A-frags + 2 B-frags (6 ds_read_b128)
// -> stage issue -> barrier -> (compiler lgkmcnt) -> 8 MFMA 32x32x16.
#define GPHASE32(KS, S, STAGE_CODE, VM) do { \
    f16x8 af[4], bb[2]; \
    _Pragma("unroll") \
    for (int mt = 0; mt < 4; ++mt) \
        af[mt] = *(const f16x8*)(smem + ((bufo + (KS) * 16384 + abase[mt]) ^ ((S) << 5))); \
    _Pragma("unroll") \
    for (int nt = 0; nt < 2; ++nt) \
        bb[nt] = *(const f16x8*)(smem + ((bufo + (KS) * 16384 + bbase[nt]) ^ ((S) << 5))); \
    STAGE_CODE; \
    __builtin_amdgcn_sched_barrier(0); \
    __builtin_amdgcn_s_barrier(); \
    __builtin_amdgcn_sched_barrier(0); \
    __builtin_amdgcn_s_setprio(1); \
    _Pragma("unroll") \
    for (int mt = 0; mt < 4; ++mt) \
        _Pragma("unroll") \
        for (int nt = 0; nt < 2; ++nt) \
            acc[mt][nt] = __builtin_amdgcn_mfma_f32_32x32x16_f16( \
                af[mt], bb[nt], acc[mt][nt], 0, 0, 0); \
    __builtin_amdgcn_s_setprio(0); \
    VM; \
    __builtin_amdgcn_sched_barrier(0); \
    __builtin_amdgcn_s_barrier(); \
    __builtin_amdgcn_sched_barrier(0); \
} while (0)

template<int CMODE>
__global__ __launch_bounds__(512, 2)
void gemm256(const f16* __restrict__ A, const f16* __restrict__ B,
             void* __restrict__ Cv,
             int M, int N, int K, int lda, int ldb, int ldc,
             long az, long bz, long cz,
             float* __restrict__ pm, float* __restrict__ ps)
{
    __shared__ __align__(16) char smem[131072];

    const int z = blockIdx.z;
    const char* Ab = (const char*)(A + z * az);
    const char* Bb = (const char*)(B + z * bz);

    // XCD-aware swizzle (all launches have nwg % 8 == 0)
    const int nbx = N >> 8;
    int wg = blockIdx.x;
    const int nwg = gridDim.x;
    if ((nwg & 7) == 0) wg = (wg & 7) * (nwg >> 3) + (wg >> 3);
    const int bm = (wg / nbx) << 8;
    const int bn = (wg % nbx) << 8;

    const int tid = threadIdx.x;
    const int wave = tid >> 6;
    const int lane = tid & 63;
    const int l31 = lane & 31;
    const int h5 = lane >> 5;
    const int wm = wave >> 2;      // 0..1 -> rows wm*128..+128
    const int wn = wave & 3;       // 0..3 -> cols wn*64..+64

    // swizzled slot: slot = (2*S ^ h5 ^ f) with f = (row ^ row>>2)&3
    const int f3 = (l31 ^ (l31 >> 2)) & 3;
    const int sl = ((h5 ^ f3) << 4);
    int abase[4], bbase[2];
    #pragma unroll
    for (int mt = 0; mt < 4; ++mt)
        abase[mt] = (wm * 128 + mt * 32 + l31) * 64 + sl;
    #pragma unroll
    for (int nt = 0; nt < 2; ++nt)
        bbase[nt] = 32768 + (wn * 64 + nt * 32 + l31) * 64 + sl;

    // staging per-thread constants
    const int srow0 = tid >> 2;
    const int sh8 = ((tid ^ (tid >> 2) ^ (tid >> 4)) & 3) * 8;

    f32x16 acc[4][2];
    #pragma unroll
    for (int mt = 0; mt < 4; ++mt)
        #pragma unroll
        for (int nt = 0; nt < 2; ++nt)
            acc[mt][nt] = (f32x16)(0.f);

    const int nt_k = K >> 6;

    {
        const int t1p = (nt_k > 1) ? 1 : 0;
        STAGE(0, 0, 0, 0);
        STAGE(1, 0, 0, 0);
        STAGE(0, 1, 0, 0);
        STAGE(1, 1, 0, 0);
        STAGE(0, 0, t1p, 65536);
        STAGE(1, 0, t1p, 65536);
        asm volatile("s_waitcnt vmcnt(4)" ::: "memory");
        __builtin_amdgcn_sched_barrier(0);
        __builtin_amdgcn_s_barrier();
        __builtin_amdgcn_sched_barrier(0);
    }

    for (int t = 0; t < nt_k; ++t) {
        const int bufo = (t & 1) << 16;
        const int nbo = bufo ^ 65536;
        const int t1 = (t + 1 < nt_k) ? t + 1 : nt_k - 1;
        const int t2 = (t + 2 < nt_k) ? t + 2 : nt_k - 1;
        GPHASE32(0, 0, STAGE(0, 1, t1, nbo), );
        GPHASE32(0, 1, STAGE(1, 1, t1, nbo), );
        GPHASE32(1, 0, STAGE(0, 0, t2, bufo), );
        GPHASE32(1, 1, STAGE(1, 0, t2, bufo),
                 asm volatile("s_waitcnt vmcnt(4)" ::: "memory"));
    }
    // drain pending LDS-DMA before the workgroup can exit
    asm volatile("s_waitcnt vmcnt(0)" ::: "memory");

    // ---- epilogue: 32x32 D mapping col=lane&31, row=(reg&3)+4*(lane>>5)+8*(reg>>2)
    if (CMODE == CM_ATTN) {
        f16* E = (f16*)Cv + z * cz;
        #pragma unroll
        for (int nt = 0; nt < 2; ++nt) {
            float Mx = -3.4e38f;
            #pragma unroll
            for (int mt = 0; mt < 4; ++mt)
                #pragma unroll
                for (int r = 0; r < 16; ++r)
                    Mx = fmaxf(Mx, acc[mt][nt][r]);
            Mx = fmaxf(Mx, __shfl_xor(Mx, 32, 64));
            float Sm = 0.f;
            #pragma unroll
            for (int mt = 0; mt < 4; ++mt)
                #pragma unroll
                for (int r = 0; r < 16; ++r) {
                    const float e = exp2f((acc[mt][nt][r] - Mx) * LOG2E);
                    acc[mt][nt][r] = e;
                    Sm += e;
                }
            Sm += __shfl_xor(Sm, 32, 64);
            const int col = bn + wn * 64 + nt * 32 + l31;
            #pragma unroll
            for (int mt = 0; mt < 4; ++mt) {
                const int row0 = bm + wm * 128 + mt * 32 + h5 * 4;
                #pragma unroll
                for (int rq = 0; rq < 4; ++rq)
                    #pragma unroll
                    for (int rr = 0; rr < 4; ++rr)
                        E[(long)(row0 + rq * 8 + rr) * ldc + col] =
                            (f16)acc[mt][nt][rq * 4 + rr];
            }
            if (lane < 32) {
                const long pidx = ((long)z * 16 + (bm >> 7) + wm) * N + col;
                pm[pidx] = Mx * LOG2E;   // log2 domain
                ps[pidx] = Sm;
            }
        }
        return;
    }

    #pragma unroll
    for (int mt = 0; mt < 4; ++mt) {
        #pragma unroll
        for (int nt = 0; nt < 2; ++nt) {
            const int row0 = bm + wm * 128 + mt * 32 + h5 * 4;
            const int col = bn + wn * 64 + nt * 32 + l31;
            if (CMODE == CM_F32) {
                float* C = (float*)Cv + z * cz;
                #pragma unroll
                for (int rq = 0; rq < 4; ++rq)
                    #pragma unroll
                    for (int rr = 0; rr < 4; ++rr)
                        C[(long)(row0 + rq * 8 + rr) * ldc + col] =
                            acc[mt][nt][rq * 4 + rr];
            } else if (CMODE == CM_PACK_HH || CMODE == CM_PACK_HL) {
                f16* C = (f16*)Cv + z * cz;
                #pragma unroll
                for (int rq = 0; rq < 4; ++rq)
                    #pragma unroll
                    for (int rr = 0; rr < 4; ++rr) {
                        const float v = acc[mt][nt][rq * 4 + rr];
                        const f16 h = (f16)v;
                        const long base = (long)(row0 + rq * 8 + rr) * (2LL * N) + col;
                        C[base] = h;
                        C[base + N] = (CMODE == CM_PACK_HH) ? h : (f16)(v - (float)h);
                    }
            } else { // CM_F16T: C^T[col][rows]
                f16* C = (f16*)Cv + z * cz;
                #pragma unroll
                for (int rq = 0; rq < 4; ++rq) {
                    f16x4 v;
                    #pragma unroll
                    for (int rr = 0; rr < 4; ++rr) v[rr] = (f16)acc[mt][nt][rq * 4 + rr];
                    *(f16x4*)(C + (long)col * ldc + row0 + rq * 8) = v;
                }
            }
        }
    }
}

// ---------------------------------------------------------------------------
// q rows: fp32 [R,1024] -> f16 [R,1024] cast AND fp32 copy into out[:,0:1024]
// (out row stride 2048)
// ---------------------------------------------------------------------------
__global__ __launch_bounds__(256)
void pack_cast_q(const float* __restrict__ in, f16* __restrict__ op,
                 float* __restrict__ oq, long nquads)
{
    const long i = (long)blockIdx.x * 256 + threadIdx.x;
    if (i >= nquads) return;
    const long row = i >> 8;
    const int c = (int)(i & 255) * 4;
    const float4 v = *(const float4*)(in + row * 1024 + c);
    *(float4*)(oq + row * 2048 + c) = v;
    f16x4 h;
    h[0] = (f16)v.x; h[1] = (f16)v.y; h[2] = (f16)v.z; h[3] = (f16)v.w;
    *(f16x4*)(op + row * 1024 + c) = h;
}

// k rows: fp32 [R,1024] -> f16 [R,1024]
__global__ __launch_bounds__(256)
void pack_cast_k(const float* __restrict__ in, f16* __restrict__ op, long nquads)
{
    const long i = (long)blockIdx.x * 256 + threadIdx.x;
    if (i >= nquads) return;
    const long row = i >> 8;
    const int c = (int)(i & 255) * 4;
    const float4 v = *(const float4*)(in + row * 1024 + c);
    f16x4 h;
    h[0] = (f16)v.x; h[1] = (f16)v.y; h[2] = (f16)v.z; h[3] = (f16)v.w;
    *(f16x4*)(op + row * 1024 + c) = h;
}

// ---------------------------------------------------------------------------
// W [1024 d][1024 o] fp32 -> Wt [1024 o][1024 d] f16 (transpose + cast)
// ---------------------------------------------------------------------------
__global__ __launch_bounds__(256)
void pack_W_T(const float* __restrict__ W, f16* __restrict__ Wt)
{
    __shared__ float tile[64][65];
    const int d0 = blockIdx.y * 64, o0 = blockIdx.x * 64;
    const int t = threadIdx.x;
    const int rr = t >> 4, c4 = (t & 15) * 4;
    #pragma unroll
    for (int it = 0; it < 4; ++it) {
        const int r = rr + it * 16;
        const float4 v = *(const float4*)(W + (long)(d0 + r) * 1024 + o0 + c4);
        tile[r][c4] = v.x; tile[r][c4 + 1] = v.y;
        tile[r][c4 + 2] = v.z; tile[r][c4 + 3] = v.w;
    }
    __syncthreads();
    #pragma unroll
    for (int it = 0; it < 4; ++it) {
        const int orow = rr + it * 16;
        f16x4 h;
        #pragma unroll
        for (int j = 0; j < 4; ++j) h[j] = (f16)tile[c4 + j][orow];
        *(f16x4*)(Wt + (long)(o0 + orow) * 1024 + d0 + c4) = h;
    }
}

// ---------------------------------------------------------------------------
// merge 16 per-block partials -> scale[z][16][2048] = exp2(pm - L)
// ---------------------------------------------------------------------------
__global__ __launch_bounds__(256)
void softmax_merge16(const float* __restrict__ pm, const float* __restrict__ ps,
                     float* __restrict__ scale, int nq)
{
    const int idx = blockIdx.x * 256 + threadIdx.x;
    if (idx >= nq) return;
    const int z = idx >> 11, q = idx & 2047;
    const float* pmz = pm + ((long)z * 16) * 2048 + q;
    const float* psz = ps + ((long)z * 16) * 2048 + q;
    float mx = -3.4e38f;
    #pragma unroll
    for (int j = 0; j < 16; ++j) mx = fmaxf(mx, pmz[j * 2048]);
    float s = 0.f;
    #pragma unroll
    for (int j = 0; j < 16; ++j)
        s += psz[j * 2048] * exp2f(pmz[j * 2048] - mx);
    const float L = mx + log2f(s);
    float* sc = scale + ((long)z * 16) * 2048 + q;
    #pragma unroll
    for (int j = 0; j < 16; ++j)
        sc[j * 2048] = exp2f(pmz[j * 2048] - L);
}

// ---------------------------------------------------------------------------
// in-place rescale: e[z][kk][q] *= scale[z][kk>>7][q]   (8 f16 per thread)
// ---------------------------------------------------------------------------
__global__ __launch_bounds__(256)
void rescale_e(f16* __restrict__ e, const float* __restrict__ scale, long n8)
{
    const long idx = (long)blockIdx.x * 256 + threadIdx.x;
    if (idx >= n8) return;
    const long z = idx >> 19;                 // 2^19 groups of 8 per z
    const int within = (int)(idx & ((1 << 19) - 1));
    const int kk = within >> 8;
    const int q8 = (within & 255) * 8;
    const float* sc = scale + ((long)z * 16 + (kk >> 7)) * 2048 + q8;
    const float4 s0 = *(const float4*)sc;
    const float4 s1 = *(const float4*)(sc + 4);
    f16x8 v = *(f16x8*)(e + idx * 8);
    v[0] = (f16)((float)v[0] * s0.x); v[1] = (f16)((float)v[1] * s0.y);
    v[2] = (f16)((float)v[2] * s0.z); v[3] = (f16)((float)v[3] * s0.w);
    v[4] = (f16)((float)v[4] * s1.x); v[5] = (f16)((float)v[5] * s1.y);
    v[6] = (f16)((float)v[6] * s1.z); v[7] = (f16)((float)v[7] * s1.w);
    *(f16x8*)(e + idx * 8) = v;
}

// ---------------------------------------------------------------------------
__global__ __launch_bounds__(256)
void copy_q_kernel(const float* __restrict__ q, float* __restrict__ out, long n4)
{
    const long idx = (long)blockIdx.x * 256 + threadIdx.x;
    if (idx >= n4) return;
    const long row = idx >> 8;
    const long c4 = idx & 255;
    *(float4*)(&out[row * 2048 + c4 * 4]) =
        *(const float4*)(&q[row * 1024 + c4 * 4]);
}

// ===========================================================================
// fp32 fallback for small workspaces
// ===========================================================================
#define BM 64
#define BN 64
#define BKF 16
template<int opA, int opB>
__global__ __launch_bounds__(256)
void sgemm(const float* __restrict__ A, const float* __restrict__ B,
           float* __restrict__ C,
           int M, int N, int K, int lda, int ldb, int ldc)
{
    __shared__ float As[BKF][BM];
    __shared__ float Bs[BKF][BN];
    const int tid = threadIdx.x;
    const int tx = tid & 15, ty = tid >> 4;
    const int bm = blockIdx.y * BM, bn = blockIdx.x * BN;
    float acc[4][4] = {};
    for (int k0 = 0; k0 < K; k0 += BKF) {
        if (opA == 0) {
            const int row = tid >> 2, kq = (tid & 3) * 4;
            const float4 v = *(const float4*)(A + (long)(bm + row) * lda + (k0 + kq));
            As[kq + 0][row] = v.x; As[kq + 1][row] = v.y;
            As[kq + 2][row] = v.z; As[kq + 3][row] = v.w;
        } else {
            const int kk = tid >> 4, mq = (tid & 15) * 4;
            *(float4*)(&As[kk][mq]) =
                *(const float4*)(A + (long)(k0 + kk) * lda + (bm + mq));
        }
        if (opB == 0) {
            const int kk = tid >> 4, nq = (tid & 15) * 4;
            *(float4*)(&Bs[kk][nq]) =
                *(const float4*)(B + (long)(k0 + kk) * ldb + (bn + nq));
        } else {
            const int row = tid >> 2, kq = (tid & 3) * 4;
            const float4 v = *(const float4*)(B + (long)(bn + row) * ldb + (k0 + kq));
            Bs[kq + 0][row] = v.x; Bs[kq + 1][row] = v.y;
            Bs[kq + 2][row] = v.z; Bs[kq + 3][row] = v.w;
        }
        __syncthreads();
        #pragma unroll
        for (int kk = 0; kk < BKF; ++kk) {
            const float4 a = *(const float4*)(&As[kk][ty * 4]);
            const float4 b = *(const float4*)(&Bs[kk][tx * 4]);
            const float av[4] = {a.x, a.y, a.z, a.w};
            const float bv[4] = {b.x, b.y, b.z, b.w};
            #pragma unroll
            for (int i = 0; i < 4; ++i)
                #pragma unroll
                for (int j = 0; j < 4; ++j)
                    acc[i][j] += av[i] * bv[j];
        }
        __syncthreads();
    }
    #pragma unroll
    for (int i = 0; i < 4; ++i) {
        const float4 v = make_float4(acc[i][0], acc[i][1], acc[i][2], acc[i][3]);
        *(float4*)(&C[(long)(bm + ty * 4 + i) * ldc + (bn + tx * 4)]) = v;
    }
}

__device__ __forceinline__ float wave_reduce_max(float v) {
    #pragma unroll
    for (int off = 1; off < 64; off <<= 1)
        v = fmaxf(v, __shfl_xor(v, off, 64));
    return v;
}
__device__ __forceinline__ float wave_reduce_sum(float v) {
    #pragma unroll
    for (int off = 1; off < 64; off <<= 1)
        v += __shfl_xor(v, off, 64);
    return v;
}

__global__ __launch_bounds__(256)
void softmax_rows2048(float* __restrict__ X)
{
    float* x = X + (long)blockIdx.x * 2048;
    const int tid = threadIdx.x;
    float4 v0 = *(const float4*)(&x[tid * 4]);
    float4 v1 = *(const float4*)(&x[1024 + tid * 4]);
    float m = fmaxf(fmaxf(fmaxf(v0.x, v0.y), fmaxf(v0.z, v0.w)),
                    fmaxf(fmaxf(v1.x, v1.y), fmaxf(v1.z, v1.w)));
    m = wave_reduce_max(m);
    __shared__ float sm[4];
    __shared__ float ss[4];
    const int wid = tid >> 6;
    if ((tid & 63) == 0) sm[wid] = m;
    __syncthreads();
    m = fmaxf(fmaxf(sm[0], sm[1]), fmaxf(sm[2], sm[3]));
    v0.x = expf(v0.x - m); v0.y = expf(v0.y - m);
    v0.z = expf(v0.z - m); v0.w = expf(v0.w - m);
    v1.x = expf(v1.x - m); v1.y = expf(v1.y - m);
    v1.z = expf(v1.z - m); v1.w = expf(v1.w - m);
    float s = (v0.x + v0.y + v0.z + v0.w) + (v1.x + v1.y + v1.z + v1.w);
    s = wave_reduce_sum(s);
    if ((tid & 63) == 0) ss[wid] = s;
    __syncthreads();
    s = ss[0] + ss[1] + ss[2] + ss[3];
    const float inv = 1.0f / s;
    v0.x *= inv; v0.y *= inv; v0.z *= inv; v0.w *= inv;
    v1.x *= inv; v1.y *= inv; v1.z *= inv; v1.w *= inv;
    *(float4*)(&x[tid * 4]) = v0;
    *(float4*)(&x[1024 + tid * 4]) = v1;
}

static void fallback_fp32(const float* q, const float* k, const float* Wq,
                          const float* Wk, const float* Wv, float* out,
                          void* d_ws, hipStream_t stream)
{
    const int S = 2048, D = 1024, O = 1024, B = 8;
    float* qp = (float*)d_ws;
    float* kp = qp + (size_t)S * O;
    float* vp = kp + (size_t)S * O;
    float* attn = vp + (size_t)S * O;
    const long n4 = (long)B * S * D / 4;
    copy_q_kernel<<<dim3((n4 + 255) / 256), 256, 0, stream>>>(q, out, n4);
    const dim3 blk(256);
    const dim3 gproj(O / BN, S / BM), gattn(S / BN, S / BM), gctx(O / BN, S / BM);
    for (int b = 0; b < B; ++b) {
        const float* qb = q + (size_t)b * S * D;
        const float* kb = k + (size_t)b * S * D;
        float* outc = out + (size_t)b * S * 2048 + D;
        sgemm<0, 0><<<gproj, blk, 0, stream>>>(qb, Wq, qp, S, O, D, D, O, O);
        sgemm<0, 0><<<gproj, blk, 0, stream>>>(kb, Wk, kp, S, O, D, D, O, O);
        sgemm<0, 0><<<gproj, blk, 0, stream>>>(kb, Wv, vp, S, O, D, D, O, O);
        sgemm<0, 1><<<gattn, blk, 0, stream>>>(qp, kp, attn, S, S, O, O, O, S);
        softmax_rows2048<<<dim3(S), blk, 0, stream>>>(attn);
        sgemm<1, 0><<<gctx, blk, 0, stream>>>(attn, vp, outc, S, O, S, S, O, 2048);
    }
}

// ===========================================================================
extern "C" void kernel_launch(void* const* d_in, const int* in_sizes, int n_in,
                              void* d_out, int out_size, void* d_ws, size_t ws_size,
                              hipStream_t stream)
{
    const float* q  = (const float*)d_in[0];
    const float* k  = (const float*)d_in[1];
    const float* Wq = (const float*)d_in[2];
    const float* Wk = (const float*)d_in[3];
    const float* Wv = (const float*)d_in[4];
    float* out = (float*)d_out;

    const int B = 8, S = 2048;

    auto need = [](int g) -> size_t {
        const size_t wpk = 3 * (size_t)1024 * 1024 * 2;
        const size_t pkA = (size_t)g * 2048 * 1024 * 2;   // qpack, kpack
        const size_t pk2 = (size_t)g * 2048 * 2048 * 2;   // qp_pack, kp_pack
        const size_t vpT = (size_t)1024 * g * 2048 * 2;
        const size_t aw  = (size_t)g * 2048 * 2048 * 2;
        const size_t pp  = 3 * (size_t)g * 16 * 2048 * 4;
        return wpk + 2 * pkA + 2 * pk2 + vpT + aw + pp + 32 * 256;
    };
    int g = 0;
    for (int cand : {8, 4, 2, 1})
        if (need(cand) <= ws_size) { g = cand; break; }
    if (g == 0) { fallback_fp32(q, k, Wq, Wk, Wv, out, d_ws, stream); return; }

    char* p = (char*)d_ws;
    auto carve = [&](size_t bytes) {
        char* r = p;
        p += (bytes + 255) & ~(size_t)255;
        return r;
    };
    f16* Wtq = (f16*)carve((size_t)1024 * 1024 * 2);
    f16* Wtk = (f16*)carve((size_t)1024 * 1024 * 2);
    f16* Wtv = (f16*)carve((size_t)1024 * 1024 * 2);
    const size_t pkAB = (size_t)g * 2048 * 1024 * 2;
    const size_t pk2B = (size_t)g * 2048 * 2048 * 2;
    f16* qpack   = (f16*)carve(pkAB);
    f16* kpack   = (f16*)carve(pkAB);
    f16* qp_pack = (f16*)carve(pk2B);
    f16* kp_pack = (f16*)carve(pk2B);
    f16* vpT     = (f16*)carve((size_t)1024 * g * 2048 * 2);
    f16* attn_w  = (f16*)carve((size_t)g * 2048 * 2048 * 2);
    float* pmb   = (float*)carve((size_t)g * 16 * 2048 * 4);
    float* psb   = (float*)carve((size_t)g * 16 * 2048 * 4);
    float* scb   = (float*)carve((size_t)g * 16 * 2048 * 4);

    pack_W_T<<<dim3(16, 16), 256, 0, stream>>>(Wq, Wtq);
    pack_W_T<<<dim3(16, 16), 256, 0, stream>>>(Wk, Wtk);
    pack_W_T<<<dim3(16, 16), 256, 0, stream>>>(Wv, Wtv);

    const int Mg = g * 2048;
    const dim3 blk(256);
    const dim3 blk512(512);
    const long zSS = (long)2048 * 2048;

    for (int gi = 0; gi < B / g; ++gi) {
        const float* qg = q + (size_t)gi * Mg * 1024;
        const float* kg = k + (size_t)gi * Mg * 1024;
        float* outq = out + (size_t)gi * Mg * 2048;

        const long nquads = (long)Mg * 256;
        pack_cast_q<<<dim3((nquads + 255) / 256), blk, 0, stream>>>(
            qg, qpack, outq, nquads);
        pack_cast_k<<<dim3((nquads + 255) / 256), blk, 0, stream>>>(
            kg, kpack, nquads);

        // projections: plain fp16, K=1024
        const dim3 g1((1024 / 256) * (Mg / 256), 1, 1);
        gemm256<CM_PACK_HH><<<g1, blk512, 0, stream>>>(
            qpack, Wtq, qp_pack, Mg, 1024, 1024, 1024, 1024, 0, 0, 0, 0,
            nullptr, nullptr);
        gemm256<CM_PACK_HL><<<g1, blk512, 0, stream>>>(
            kpack, Wtk, kp_pack, Mg, 1024, 1024, 1024, 1024, 0, 0, 0, 0,
            nullptr, nullptr);
        gemm256<CM_F16T><<<g1, blk512, 0, stream>>>(
            kpack, Wtv, vpT, Mg, 1024, 1024, 1024, 1024, Mg, 0, 0, 0,
            nullptr, nullptr);

        // attnT = kp @ qp^T per z (K'=2048, 2-term K side) -> f16 e + partials
        const dim3 g2((2048 / 256) * (2048 / 256), 1, g);
        gemm256<CM_ATTN><<<g2, blk512, 0, stream>>>(
            kp_pack, qp_pack, attn_w, 2048, 2048, 2048, 2048, 2048, 2048,
            zSS, zSS, zSS, pmb, psb);

        // merge partials -> scale table; in-place rescale e -> weights
        const int nq = g * 2048;
        softmax_merge16<<<dim3((nq + 255) / 256), blk, 0, stream>>>(pmb, psb, scb, nq);
        const long n8 = (long)g * 2048 * 256;
        rescale_e<<<dim3((n8 + 255) / 256), blk, 0, stream>>>(attn_w, scb, n8);

        // context = attn_w @ vpT^T -> out cols 1024..2047
        float* outg = out + (size_t)gi * Mg * 2048 + 1024;
        const dim3 g3((1024 / 256) * (2048 / 256), 1, g);
        gemm256<CM_F32><<<g3, blk512, 0, stream>>>(
            attn_w, vpT, outg, 2048, 1024, 2048, 2048, Mg, 2048,
            zSS, 2048, zSS, nullptr, nullptr);
    }
}

// Round 7
// 376.182 us; speedup vs baseline: 9.8119x; 1.2046x over previous
//
#include <hip/hip_runtime.h>
#include <hip/hip_bf16.h>

// B=8, S=2048, D=1024, O=1024
// qp=q@Wq, kp=k@Wk, vp=k@Wv ; attn=qp@kp^T (no scale); w=softmax(attn,-1)
// context = attn_w^T @ vp ; out = concat([q, context], -1)  fp32 [B,S,2048]
//
// Precision plan (validated by absmax invariance r4-r6): ALL GEMMs plain
// fp16 inputs, fp32 MFMA accumulate. Logit RMS error ~0.014 (non-binding);
// binding error is f16 attn-weight quantization (~0.06 absmax, threshold
// 0.2225). attnT = kp @ qp^T computed transposed; epilogue writes f16
// e=exp(l-M_blk) + per-128-row partials; merge -> scale table; in-place
// rescale; PV consumes weights directly.
//
// GEMM: 256x256 tile, BK=64, 8 waves (2Mx4N), 32x32x16 f16 MFMA (8/phase),
// 4 phases/K-tile, counted vmcnt(4), setprio, XCD swizzle, conflict-free LDS.

typedef __attribute__((ext_vector_type(4))) float f32x4;
typedef __attribute__((ext_vector_type(16))) float f32x16;
typedef _Float16 f16;
typedef __attribute__((ext_vector_type(8))) _Float16 f16x8;
typedef __attribute__((ext_vector_type(4))) _Float16 f16x4;

#define LOG2E 1.4426950408889634f

#define CM_F32     0
#define CM_F16     1
#define CM_F16T    3
#define CM_ATTN    4

// Stage one 16 KiB unit (WHICH: 0=A,1=B; KS: k-half) of K-tile KT into buffer
// at byte offset BO. LDS dst linear in tid; XOR swizzle applied by
// pre-swizzling the GLOBAL source k-chunk (both-sides-or-neither).
#define STAGE(WHICH, KS, KT, BO) do { \
    const char* _gb = (WHICH) ? Bb : Ab; \
    const int _ld = (WHICH) ? ldb : lda; \
    const long _r = (WHICH) ? (long)(bn + srow0) : (long)(bm + srow0); \
    const int _k0 = (KT) * 64 + (KS) * 32 + sh8; \
    char* _dst = (char*)smem + (BO) + (WHICH) * 32768 + (KS) * 16384 + wave * 1024; \
    const char* _g0 = _gb + ((_r * _ld + _k0) << 1); \
    const char* _g1 = _gb + (((_r + 128) * _ld + _k0) << 1); \
    __builtin_amdgcn_global_load_lds((const __attribute__((address_space(1))) void*)_g0, \
        (__attribute__((address_space(3))) void*)_dst, 16, 0, 0); \
    __builtin_amdgcn_global_load_lds((const __attribute__((address_space(1))) void*)_g1, \
        (__attribute__((address_space(3))) void*)(_dst + 8192), 16, 0, 0); \
} while (0)

// One phase: k-step S (0/1) of unit KS. 4 A-frags + 2 B-frags (6 ds_read_b128)
// -> stage issue -> barrier -> (compiler lgkmcnt) -> 8 MFMA 32x32x16.
#define GPHASE32(KS, S, STAGE_CODE, VM) do { \
    f16x8 af[4], bb[2]; \
    _Pragma("unroll") \
    for (int mt = 0; mt < 4; ++mt) \
        af[mt] = *(const f16x8*)(smem + ((bufo + (KS) * 16384 + abase[mt]) ^ ((S) << 5))); \
    _Pragma("unroll") \
    for (int nt = 0; nt < 2; ++nt) \
        bb[nt] = *(const f16x8*)(smem + ((bufo + (KS) * 16384 + bbase[nt]) ^ ((S) << 5))); \
    STAGE_CODE; \
    __builtin_amdgcn_sched_barrier(0); \
    __builtin_amdgcn_s_barrier(); \
    __builtin_amdgcn_sched_barrier(0); \
    __builtin_amdgcn_s_setprio(1); \
    _Pragma("unroll") \
    for (int mt = 0; mt < 4; ++mt) \
        _Pragma("unroll") \
        for (int nt = 0; nt < 2; ++nt) \
            acc[mt][nt] = __builtin_amdgcn_mfma_f32_32x32x16_f16( \
                af[mt], bb[nt], acc[mt][nt], 0, 0, 0); \
    __builtin_amdgcn_s_setprio(0); \
    VM; \
    __builtin_amdgcn_sched_barrier(0); \
    __builtin_amdgcn_s_barrier(); \
    __builtin_amdgcn_sched_barrier(0); \
} while (0)

template<int CMODE>
__global__ __launch_bounds__(512, 2)
void gemm256(const f16* __restrict__ A, const f16* __restrict__ B,
             void* __restrict__ Cv,
             int M, int N, int K, int lda, int ldb, int ldc,
             long az, long bz, long cz,
             float* __restrict__ pm, float* __restrict__ ps)
{
    __shared__ __align__(16) char smem[131072];

    const int z = blockIdx.z;
    const char* Ab = (const char*)(A + z * az);
    const char* Bb = (const char*)(B + z * bz);

    // XCD-aware swizzle (all launches have nwg % 8 == 0)
    const int nbx = N >> 8;
    int wg = blockIdx.x;
    const int nwg = gridDim.x;
    if ((nwg & 7) == 0) wg = (wg & 7) * (nwg >> 3) + (wg >> 3);
    const int bm = (wg / nbx) << 8;
    const int bn = (wg % nbx) << 8;

    const int tid = threadIdx.x;
    const int wave = tid >> 6;
    const int lane = tid & 63;
    const int l31 = lane & 31;
    const int h5 = lane >> 5;
    const int wm = wave >> 2;      // 0..1 -> rows wm*128..+128
    const int wn = wave & 3;       // 0..3 -> cols wn*64..+64

    // swizzled slot: slot = (2*S ^ h5 ^ f) with f = (row ^ row>>2)&3
    const int f3 = (l31 ^ (l31 >> 2)) & 3;
    const int sl = ((h5 ^ f3) << 4);
    int abase[4], bbase[2];
    #pragma unroll
    for (int mt = 0; mt < 4; ++mt)
        abase[mt] = (wm * 128 + mt * 32 + l31) * 64 + sl;
    #pragma unroll
    for (int nt = 0; nt < 2; ++nt)
        bbase[nt] = 32768 + (wn * 64 + nt * 32 + l31) * 64 + sl;

    // staging per-thread constants
    const int srow0 = tid >> 2;
    const int sh8 = ((tid ^ (tid >> 2) ^ (tid >> 4)) & 3) * 8;

    f32x16 acc[4][2];
    #pragma unroll
    for (int mt = 0; mt < 4; ++mt)
        #pragma unroll
        for (int nt = 0; nt < 2; ++nt)
            acc[mt][nt] = (f32x16)(0.f);

    const int nt_k = K >> 6;

    {
        const int t1p = (nt_k > 1) ? 1 : 0;
        STAGE(0, 0, 0, 0);
        STAGE(1, 0, 0, 0);
        STAGE(0, 1, 0, 0);
        STAGE(1, 1, 0, 0);
        STAGE(0, 0, t1p, 65536);
        STAGE(1, 0, t1p, 65536);
        asm volatile("s_waitcnt vmcnt(4)" ::: "memory");
        __builtin_amdgcn_sched_barrier(0);
        __builtin_amdgcn_s_barrier();
        __builtin_amdgcn_sched_barrier(0);
    }

    for (int t = 0; t < nt_k; ++t) {
        const int bufo = (t & 1) << 16;
        const int nbo = bufo ^ 65536;
        const int t1 = (t + 1 < nt_k) ? t + 1 : nt_k - 1;
        const int t2 = (t + 2 < nt_k) ? t + 2 : nt_k - 1;
        GPHASE32(0, 0, STAGE(0, 1, t1, nbo), );
        GPHASE32(0, 1, STAGE(1, 1, t1, nbo), );
        GPHASE32(1, 0, STAGE(0, 0, t2, bufo), );
        GPHASE32(1, 1, STAGE(1, 0, t2, bufo),
                 asm volatile("s_waitcnt vmcnt(4)" ::: "memory"));
    }
    // drain pending LDS-DMA before the workgroup can exit
    asm volatile("s_waitcnt vmcnt(0)" ::: "memory");

    // ---- epilogue: 32x32 D mapping col=lane&31, row=(reg&3)+4*(lane>>5)+8*(reg>>2)
    if (CMODE == CM_ATTN) {
        f16* E = (f16*)Cv + z * cz;
        #pragma unroll
        for (int nt = 0; nt < 2; ++nt) {
            float Mx = -3.4e38f;
            #pragma unroll
            for (int mt = 0; mt < 4; ++mt)
                #pragma unroll
                for (int r = 0; r < 16; ++r)
                    Mx = fmaxf(Mx, acc[mt][nt][r]);
            Mx = fmaxf(Mx, __shfl_xor(Mx, 32, 64));
            float Sm = 0.f;
            #pragma unroll
            for (int mt = 0; mt < 4; ++mt)
                #pragma unroll
                for (int r = 0; r < 16; ++r) {
                    const float e = exp2f((acc[mt][nt][r] - Mx) * LOG2E);
                    acc[mt][nt][r] = e;
                    Sm += e;
                }
            Sm += __shfl_xor(Sm, 32, 64);
            const int col = bn + wn * 64 + nt * 32 + l31;
            #pragma unroll
            for (int mt = 0; mt < 4; ++mt) {
                const int row0 = bm + wm * 128 + mt * 32 + h5 * 4;
                #pragma unroll
                for (int rq = 0; rq < 4; ++rq)
                    #pragma unroll
                    for (int rr = 0; rr < 4; ++rr)
                        E[(long)(row0 + rq * 8 + rr) * ldc + col] =
                            (f16)acc[mt][nt][rq * 4 + rr];
            }
            if (lane < 32) {
                const long pidx = ((long)z * 16 + (bm >> 7) + wm) * N + col;
                pm[pidx] = Mx * LOG2E;   // log2 domain
                ps[pidx] = Sm;
            }
        }
        return;
    }

    #pragma unroll
    for (int mt = 0; mt < 4; ++mt) {
        #pragma unroll
        for (int nt = 0; nt < 2; ++nt) {
            const int row0 = bm + wm * 128 + mt * 32 + h5 * 4;
            const int col = bn + wn * 64 + nt * 32 + l31;
            if (CMODE == CM_F32) {
                float* C = (float*)Cv + z * cz;
                #pragma unroll
                for (int rq = 0; rq < 4; ++rq)
                    #pragma unroll
                    for (int rr = 0; rr < 4; ++rr)
                        C[(long)(row0 + rq * 8 + rr) * ldc + col] =
                            acc[mt][nt][rq * 4 + rr];
            } else if (CMODE == CM_F16) {
                f16* C = (f16*)Cv + z * cz;
                #pragma unroll
                for (int rq = 0; rq < 4; ++rq)
                    #pragma unroll
                    for (int rr = 0; rr < 4; ++rr)
                        C[(long)(row0 + rq * 8 + rr) * ldc + col] =
                            (f16)acc[mt][nt][rq * 4 + rr];
            } else { // CM_F16T: C^T[col][rows]
                f16* C = (f16*)Cv + z * cz;
                #pragma unroll
                for (int rq = 0; rq < 4; ++rq) {
                    f16x4 v;
                    #pragma unroll
                    for (int rr = 0; rr < 4; ++rr) v[rr] = (f16)acc[mt][nt][rq * 4 + rr];
                    *(f16x4*)(C + (long)col * ldc + row0 + rq * 8) = v;
                }
            }
        }
    }
}

// ---------------------------------------------------------------------------
// q rows: fp32 [R,1024] -> f16 [R,1024] cast AND fp32 copy into out[:,0:1024]
// (out row stride 2048)
// ---------------------------------------------------------------------------
__global__ __launch_bounds__(256)
void pack_cast_q(const float* __restrict__ in, f16* __restrict__ op,
                 float* __restrict__ oq, long nquads)
{
    const long i = (long)blockIdx.x * 256 + threadIdx.x;
    if (i >= nquads) return;
    const long row = i >> 8;
    const int c = (int)(i & 255) * 4;
    const float4 v = *(const float4*)(in + row * 1024 + c);
    *(float4*)(oq + row * 2048 + c) = v;
    f16x4 h;
    h[0] = (f16)v.x; h[1] = (f16)v.y; h[2] = (f16)v.z; h[3] = (f16)v.w;
    *(f16x4*)(op + row * 1024 + c) = h;
}

// k rows: fp32 [R,1024] -> f16 [R,1024]
__global__ __launch_bounds__(256)
void pack_cast_k(const float* __restrict__ in, f16* __restrict__ op, long nquads)
{
    const long i = (long)blockIdx.x * 256 + threadIdx.x;
    if (i >= nquads) return;
    const long row = i >> 8;
    const int c = (int)(i & 255) * 4;
    const float4 v = *(const float4*)(in + row * 1024 + c);
    f16x4 h;
    h[0] = (f16)v.x; h[1] = (f16)v.y; h[2] = (f16)v.z; h[3] = (f16)v.w;
    *(f16x4*)(op + row * 1024 + c) = h;
}

// ---------------------------------------------------------------------------
// W [1024 d][1024 o] fp32 -> Wt [1024 o][1024 d] f16 (transpose + cast)
// ---------------------------------------------------------------------------
__global__ __launch_bounds__(256)
void pack_W_T(const float* __restrict__ W, f16* __restrict__ Wt)
{
    __shared__ float tile[64][65];
    const int d0 = blockIdx.y * 64, o0 = blockIdx.x * 64;
    const int t = threadIdx.x;
    const int rr = t >> 4, c4 = (t & 15) * 4;
    #pragma unroll
    for (int it = 0; it < 4; ++it) {
        const int r = rr + it * 16;
        const float4 v = *(const float4*)(W + (long)(d0 + r) * 1024 + o0 + c4);
        tile[r][c4] = v.x; tile[r][c4 + 1] = v.y;
        tile[r][c4 + 2] = v.z; tile[r][c4 + 3] = v.w;
    }
    __syncthreads();
    #pragma unroll
    for (int it = 0; it < 4; ++it) {
        const int orow = rr + it * 16;
        f16x4 h;
        #pragma unroll
        for (int j = 0; j < 4; ++j) h[j] = (f16)tile[c4 + j][orow];
        *(f16x4*)(Wt + (long)(o0 + orow) * 1024 + d0 + c4) = h;
    }
}

// ---------------------------------------------------------------------------
// merge 16 per-block partials -> scale[z][16][2048] = exp2(pm - L)
// ---------------------------------------------------------------------------
__global__ __launch_bounds__(256)
void softmax_merge16(const float* __restrict__ pm, const float* __restrict__ ps,
                     float* __restrict__ scale, int nq)
{
    const int idx = blockIdx.x * 256 + threadIdx.x;
    if (idx >= nq) return;
    const int z = idx >> 11, q = idx & 2047;
    const float* pmz = pm + ((long)z * 16) * 2048 + q;
    const float* psz = ps + ((long)z * 16) * 2048 + q;
    float mx = -3.4e38f;
    #pragma unroll
    for (int j = 0; j < 16; ++j) mx = fmaxf(mx, pmz[j * 2048]);
    float s = 0.f;
    #pragma unroll
    for (int j = 0; j < 16; ++j)
        s += psz[j * 2048] * exp2f(pmz[j * 2048] - mx);
    const float L = mx + log2f(s);
    float* sc = scale + ((long)z * 16) * 2048 + q;
    #pragma unroll
    for (int j = 0; j < 16; ++j)
        sc[j * 2048] = exp2f(pmz[j * 2048] - L);
}

// ---------------------------------------------------------------------------
// in-place rescale: e[z][kk][q] *= scale[z][kk>>7][q]   (8 f16 per thread)
// ---------------------------------------------------------------------------
__global__ __launch_bounds__(256)
void rescale_e(f16* __restrict__ e, const float* __restrict__ scale, long n8)
{
    const long idx = (long)blockIdx.x * 256 + threadIdx.x;
    if (idx >= n8) return;
    const long z = idx >> 19;                 // 2^19 groups of 8 per z
    const int within = (int)(idx & ((1 << 19) - 1));
    const int kk = within >> 8;
    const int q8 = (within & 255) * 8;
    const float* sc = scale + ((long)z * 16 + (kk >> 7)) * 2048 + q8;
    const float4 s0 = *(const float4*)sc;
    const float4 s1 = *(const float4*)(sc + 4);
    f16x8 v = *(f16x8*)(e + idx * 8);
    v[0] = (f16)((float)v[0] * s0.x); v[1] = (f16)((float)v[1] * s0.y);
    v[2] = (f16)((float)v[2] * s0.z); v[3] = (f16)((float)v[3] * s0.w);
    v[4] = (f16)((float)v[4] * s1.x); v[5] = (f16)((float)v[5] * s1.y);
    v[6] = (f16)((float)v[6] * s1.z); v[7] = (f16)((float)v[7] * s1.w);
    *(f16x8*)(e + idx * 8) = v;
}

// ---------------------------------------------------------------------------
__global__ __launch_bounds__(256)
void copy_q_kernel(const float* __restrict__ q, float* __restrict__ out, long n4)
{
    const long idx = (long)blockIdx.x * 256 + threadIdx.x;
    if (idx >= n4) return;
    const long row = idx >> 8;
    const long c4 = idx & 255;
    *(float4*)(&out[row * 2048 + c4 * 4]) =
        *(const float4*)(&q[row * 1024 + c4 * 4]);
}

// ===========================================================================
// fp32 fallback for small workspaces
// ===========================================================================
#define BM 64
#define BN 64
#define BKF 16
template<int opA, int opB>
__global__ __launch_bounds__(256)
void sgemm(const float* __restrict__ A, const float* __restrict__ B,
           float* __restrict__ C,
           int M, int N, int K, int lda, int ldb, int ldc)
{
    __shared__ float As[BKF][BM];
    __shared__ float Bs[BKF][BN];
    const int tid = threadIdx.x;
    const int tx = tid & 15, ty = tid >> 4;
    const int bm = blockIdx.y * BM, bn = blockIdx.x * BN;
    float acc[4][4] = {};
    for (int k0 = 0; k0 < K; k0 += BKF) {
        if (opA == 0) {
            const int row = tid >> 2, kq = (tid & 3) * 4;
            const float4 v = *(const float4*)(A + (long)(bm + row) * lda + (k0 + kq));
            As[kq + 0][row] = v.x; As[kq + 1][row] = v.y;
            As[kq + 2][row] = v.z; As[kq + 3][row] = v.w;
        } else {
            const int kk = tid >> 4, mq = (tid & 15) * 4;
            *(float4*)(&As[kk][mq]) =
                *(const float4*)(A + (long)(k0 + kk) * lda + (bm + mq));
        }
        if (opB == 0) {
            const int kk = tid >> 4, nq = (tid & 15) * 4;
            *(float4*)(&Bs[kk][nq]) =
                *(const float4*)(B + (long)(k0 + kk) * ldb + (bn + nq));
        } else {
            const int row = tid >> 2, kq = (tid & 3) * 4;
            const float4 v = *(const float4*)(B + (long)(bn + row) * ldb + (k0 + kq));
            Bs[kq + 0][row] = v.x; Bs[kq + 1][row] = v.y;
            Bs[kq + 2][row] = v.z; Bs[kq + 3][row] = v.w;
        }
        __syncthreads();
        #pragma unroll
        for (int kk = 0; kk < BKF; ++kk) {
            const float4 a = *(const float4*)(&As[kk][ty * 4]);
            const float4 b = *(const float4*)(&Bs[kk][tx * 4]);
            const float av[4] = {a.x, a.y, a.z, a.w};
            const float bv[4] = {b.x, b.y, b.z, b.w};
            #pragma unroll
            for (int i = 0; i < 4; ++i)
                #pragma unroll
                for (int j = 0; j < 4; ++j)
                    acc[i][j] += av[i] * bv[j];
        }
        __syncthreads();
    }
    #pragma unroll
    for (int i = 0; i < 4; ++i) {
        const float4 v = make_float4(acc[i][0], acc[i][1], acc[i][2], acc[i][3]);
        *(float4*)(&C[(long)(bm + ty * 4 + i) * ldc + (bn + tx * 4)]) = v;
    }
}

__device__ __forceinline__ float wave_reduce_max(float v) {
    #pragma unroll
    for (int off = 1; off < 64; off <<= 1)
        v = fmaxf(v, __shfl_xor(v, off, 64));
    return v;
}
__device__ __forceinline__ float wave_reduce_sum(float v) {
    #pragma unroll
    for (int off = 1; off < 64; off <<= 1)
        v += __shfl_xor(v, off, 64);
    return v;
}

__global__ __launch_bounds__(256)
void softmax_rows2048(float* __restrict__ X)
{
    float* x = X + (long)blockIdx.x * 2048;
    const int tid = threadIdx.x;
    float4 v0 = *(const float4*)(&x[tid * 4]);
    float4 v1 = *(const float4*)(&x[1024 + tid * 4]);
    float m = fmaxf(fmaxf(fmaxf(v0.x, v0.y), fmaxf(v0.z, v0.w)),
                    fmaxf(fmaxf(v1.x, v1.y), fmaxf(v1.z, v1.w)));
    m = wave_reduce_max(m);
    __shared__ float sm[4];
    __shared__ float ss[4];
    const int wid = tid >> 6;
    if ((tid & 63) == 0) sm[wid] = m;
    __syncthreads();
    m = fmaxf(fmaxf(sm[0], sm[1]), fmaxf(sm[2], sm[3]));
    v0.x = expf(v0.x - m); v0.y = expf(v0.y - m);
    v0.z = expf(v0.z - m); v0.w = expf(v0.w - m);
    v1.x = expf(v1.x - m); v1.y = expf(v1.y - m);
    v1.z = expf(v1.z - m); v1.w = expf(v1.w - m);
    float s = (v0.x + v0.y + v0.z + v0.w) + (v1.x + v1.y + v1.z + v1.w);
    s = wave_reduce_sum(s);
    if ((tid & 63) == 0) ss[wid] = s;
    __syncthreads();
    s = ss[0] + ss[1] + ss[2] + ss[3];
    const float inv = 1.0f / s;
    v0.x *= inv; v0.y *= inv; v0.z *= inv; v0.w *= inv;
    v1.x *= inv; v1.y *= inv; v1.z *= inv; v1.w *= inv;
    *(float4*)(&x[tid * 4]) = v0;
    *(float4*)(&x[1024 + tid * 4]) = v1;
}

static void fallback_fp32(const float* q, const float* k, const float* Wq,
                          const float* Wk, const float* Wv, float* out,
                          void* d_ws, hipStream_t stream)
{
    const int S = 2048, D = 1024, O = 1024, B = 8;
    float* qp = (float*)d_ws;
    float* kp = qp + (size_t)S * O;
    float* vp = kp + (size_t)S * O;
    float* attn = vp + (size_t)S * O;
    const long n4 = (long)B * S * D / 4;
    copy_q_kernel<<<dim3((n4 + 255) / 256), 256, 0, stream>>>(q, out, n4);
    const dim3 blk(256);
    const dim3 gproj(O / BN, S / BM), gattn(S / BN, S / BM), gctx(O / BN, S / BM);
    for (int b = 0; b < B; ++b) {
        const float* qb = q + (size_t)b * S * D;
        const float* kb = k + (size_t)b * S * D;
        float* outc = out + (size_t)b * S * 2048 + D;
        sgemm<0, 0><<<gproj, blk, 0, stream>>>(qb, Wq, qp, S, O, D, D, O, O);
        sgemm<0, 0><<<gproj, blk, 0, stream>>>(kb, Wk, kp, S, O, D, D, O, O);
        sgemm<0, 0><<<gproj, blk, 0, stream>>>(kb, Wv, vp, S, O, D, D, O, O);
        sgemm<0, 1><<<gattn, blk, 0, stream>>>(qp, kp, attn, S, S, O, O, O, S);
        softmax_rows2048<<<dim3(S), blk, 0, stream>>>(attn);
        sgemm<1, 0><<<gctx, blk, 0, stream>>>(attn, vp, outc, S, O, S, S, O, 2048);
    }
}

// ===========================================================================
extern "C" void kernel_launch(void* const* d_in, const int* in_sizes, int n_in,
                              void* d_out, int out_size, void* d_ws, size_t ws_size,
                              hipStream_t stream)
{
    const float* q  = (const float*)d_in[0];
    const float* k  = (const float*)d_in[1];
    const float* Wq = (const float*)d_in[2];
    const float* Wk = (const float*)d_in[3];
    const float* Wv = (const float*)d_in[4];
    float* out = (float*)d_out;

    const int B = 8, S = 2048;

    auto need = [](int g) -> size_t {
        const size_t wpk = 3 * (size_t)1024 * 1024 * 2;
        const size_t pkA = (size_t)g * 2048 * 1024 * 2;   // qpack,kpack,qp,kp
        const size_t vpT = (size_t)1024 * g * 2048 * 2;
        const size_t aw  = (size_t)g * 2048 * 2048 * 2;
        const size_t pp  = 3 * (size_t)g * 16 * 2048 * 4;
        return wpk + 4 * pkA + vpT + aw + pp + 32 * 256;
    };
    int g = 0;
    for (int cand : {8, 4, 2, 1})
        if (need(cand) <= ws_size) { g = cand; break; }
    if (g == 0) { fallback_fp32(q, k, Wq, Wk, Wv, out, d_ws, stream); return; }

    char* p = (char*)d_ws;
    auto carve = [&](size_t bytes) {
        char* r = p;
        p += (bytes + 255) & ~(size_t)255;
        return r;
    };
    f16* Wtq = (f16*)carve((size_t)1024 * 1024 * 2);
    f16* Wtk = (f16*)carve((size_t)1024 * 1024 * 2);
    f16* Wtv = (f16*)carve((size_t)1024 * 1024 * 2);
    const size_t pkAB = (size_t)g * 2048 * 1024 * 2;
    f16* qpack   = (f16*)carve(pkAB);
    f16* kpack   = (f16*)carve(pkAB);
    f16* qp_pack = (f16*)carve(pkAB);
    f16* kp_pack = (f16*)carve(pkAB);
    f16* vpT     = (f16*)carve((size_t)1024 * g * 2048 * 2);
    f16* attn_w  = (f16*)carve((size_t)g * 2048 * 2048 * 2);
    float* pmb   = (float*)carve((size_t)g * 16 * 2048 * 4);
    float* psb   = (float*)carve((size_t)g * 16 * 2048 * 4);
    float* scb   = (float*)carve((size_t)g * 16 * 2048 * 4);

    pack_W_T<<<dim3(16, 16), 256, 0, stream>>>(Wq, Wtq);
    pack_W_T<<<dim3(16, 16), 256, 0, stream>>>(Wk, Wtk);
    pack_W_T<<<dim3(16, 16), 256, 0, stream>>>(Wv, Wtv);

    const int Mg = g * 2048;
    const dim3 blk(256);
    const dim3 blk512(512);
    const long zSS = (long)2048 * 2048;
    const long zSD = (long)2048 * 1024;

    for (int gi = 0; gi < B / g; ++gi) {
        const float* qg = q + (size_t)gi * Mg * 1024;
        const float* kg = k + (size_t)gi * Mg * 1024;
        float* outq = out + (size_t)gi * Mg * 2048;

        const long nquads = (long)Mg * 256;
        pack_cast_q<<<dim3((nquads + 255) / 256), blk, 0, stream>>>(
            qg, qpack, outq, nquads);
        pack_cast_k<<<dim3((nquads + 255) / 256), blk, 0, stream>>>(
            kg, kpack, nquads);

        // projections: plain fp16, K=1024, f16 outputs
        const dim3 g1((1024 / 256) * (Mg / 256), 1, 1);
        gemm256<CM_F16><<<g1, blk512, 0, stream>>>(
            qpack, Wtq, qp_pack, Mg, 1024, 1024, 1024, 1024, 1024, 0, 0, 0,
            nullptr, nullptr);
        gemm256<CM_F16><<<g1, blk512, 0, stream>>>(
            kpack, Wtk, kp_pack, Mg, 1024, 1024, 1024, 1024, 1024, 0, 0, 0,
            nullptr, nullptr);
        gemm256<CM_F16T><<<g1, blk512, 0, stream>>>(
            kpack, Wtv, vpT, Mg, 1024, 1024, 1024, 1024, Mg, 0, 0, 0,
            nullptr, nullptr);

        // attnT = kp @ qp^T per z (plain f16, K=1024) -> f16 e + partials
        const dim3 g2((2048 / 256) * (2048 / 256), 1, g);
        gemm256<CM_ATTN><<<g2, blk512, 0, stream>>>(
            kp_pack, qp_pack, attn_w, 2048, 2048, 1024, 1024, 1024, 2048,
            zSD, zSD, zSS, pmb, psb);

        // merge partials -> scale table; in-place rescale e -> weights
        const int nq = g * 2048;
        softmax_merge16<<<dim3((nq + 255) / 256), blk, 0, stream>>>(pmb, psb, scb, nq);
        const long n8 = (long)g * 2048 * 256;
        rescale_e<<<dim3((n8 + 255) / 256), blk, 0, stream>>>(attn_w, scb, n8);

        // context = attn_w @ vpT^T -> out cols 1024..2047
        float* outg = out + (size_t)gi * Mg * 2048 + 1024;
        const dim3 g3((1024 / 256) * (2048 / 256), 1, g);
        gemm256<CM_F32><<<g3, blk512, 0, stream>>>(
            attn_w, vpT, outg, 2048, 1024, 2048, 2048, Mg, 2048,
            zSS, 2048, zSS, nullptr, nullptr);
    }
}